// Round 2
// baseline (942.276 us; speedup 1.0000x reference)
//
#include <hip/hip_runtime.h>
#include <math.h>

#define LBL   8
#define DIM   96
#define PLANE (DIM*DIM)          // 9216
#define NVOX  (DIM*DIM*DIM)      // 884736
#define GD0 14
#define GD1 14
#define GD2 14
#define GD3 10
#define GSIZE (GD0*GD1*GD2*GD3)  // 27440
#define ST0 1960
#define ST1 140
#define ST2 10
#define CH  12                   // padded channel stride (9 used)
#define GRIDF (GSIZE*CH)         // 329280 floats

// normalized Gaussian weights, sigma=3, radius=9 (by |t|)
__constant__ float GW[10] = {
    0.13317604f, 0.12597912f, 0.10663904f, 0.08077540f, 0.05475300f,
    0.03320771f, 0.01802341f, 0.00875346f, 0.00380423f, 0.00147945f
};

// ---------------------------------------------------------------------------
// Kernel A: per-voxel softmax over labels + 4-D bilateral-grid splat.
// Block = 8x8x8 voxels (512 threads, 1 voxel each). All voxels in the block
// share the same lattice cell base (bz,by,bx) exactly (fracs are k/8).
// LDS: one privatized 720-float footprint copy PER WAVE (8 copies, 23 KB).
// Each lane walks the 16 (corner,intensity) combos in lane-rotated order
// ((step+lane)&15) with weights recomputed by bit-test selects, so lockstep
// lanes hit different LDS addresses -> no same-address ds_add serialization.
// ---------------------------------------------------------------------------
__global__ __launch_bounds__(512)
void k_softmax_splat(const float* __restrict__ U, const float* __restrict__ img,
                     float* __restrict__ q, float* __restrict__ grid)
{
    __shared__ float sg[8][720];
    const int tid = threadIdx.x;
    for (int i = tid; i < 8*720; i += 512) ((float*)sg)[i] = 0.f;
    __syncthreads();

    const int bid = blockIdx.x;
    const int bx = bid % 12;
    const int by = (bid / 12) % 12;
    const int bz = bid / 144;

    const int lx = tid & 7;
    const int ly = (tid >> 3) & 7;
    const int lz = tid >> 6;           // == wave id
    float* sgc = sg[lz];

    const int x = bx*8 + lx;
    const int y = by*8 + ly;
    const int z = bz*8 + lz;
    const int vox = z * PLANE + y * DIM + x;

    float u[9];
    float m = -1e30f;
    #pragma unroll
    for (int l = 0; l < LBL; ++l) { u[l] = U[l*NVOX + vox]; m = fmaxf(m, u[l]); }
    float ssum = 0.f;
    #pragma unroll
    for (int l = 0; l < LBL; ++l) { u[l] = expf(u[l] - m); ssum += u[l]; }
    const float inv = 1.f / ssum;
    #pragma unroll
    for (int l = 0; l < LBL; ++l) { u[l] *= inv; q[l*NVOX + vox] = u[l]; }
    u[8] = 1.0f;                       // homogeneous channel

    const float f = img[vox] * 8.0f;   // img / BETA (exact)
    int li = (int)floorf(f);
    li = li < 0 ? 0 : (li > 8 ? 8 : li);
    const float fi = f - (float)li;
    const float fz = (float)lz * 0.125f;
    const float fy = (float)ly * 0.125f;
    const float fx = (float)lx * 0.125f;

    #pragma unroll
    for (int step = 0; step < 16; ++step) {
        const int idx16 = (step + tid) & 15;
        const float wzv = (idx16 & 8) ? fz : 1.f - fz;
        const float wyv = (idx16 & 4) ? fy : 1.f - fy;
        const float wxv = (idx16 & 2) ? fx : 1.f - fx;
        const float wiv = (idx16 & 1) ? fi : 1.f - fi;
        const float w = wzv * wyv * wxv * wiv;
        const int slot = (idx16 >> 1) * 10 + li + (idx16 & 1);
        float* p = sgc + slot * 9;
        #pragma unroll
        for (int c = 0; c < 9; ++c) atomicAdd(&p[c], w * u[c]);
    }
    __syncthreads();

    for (int idx = tid; idx < 720; idx += 512) {
        float v = 0.f;
        #pragma unroll
        for (int w8 = 0; w8 < 8; ++w8) v += sg[w8][idx];
        const int c = idx % 9;
        const int s = idx / 9;
        const int g = s % 10;
        const int t = s / 10;          // i2*4 + j2*2 + k2
        const int k2 = t & 1;
        const int j2 = (t >> 1) & 1;
        const int i2 = (t >> 2) & 1;
        const int cell = (bz + i2)*ST0 + (by + j2)*ST1 + (bx + k2)*ST2 + g;
        atomicAdd(&grid[cell*CH + c], v);
    }
}

// ---------------------------------------------------------------------------
// Separable 19-tap Gaussian along axis AX (0=z,1=y,2=x), zero-padded.
// ---------------------------------------------------------------------------
template<int AX>
__global__ __launch_bounds__(256)
void k_gauss(const float* __restrict__ src, float* __restrict__ dst)
{
    const int id = blockIdx.x * 256 + threadIdx.x;
    if (id >= LBL * NVOX) return;
    const int rem = id % NVOX;
    int c, stride;
    if (AX == 0)      { c = rem / PLANE;        stride = PLANE; }
    else if (AX == 1) { c = (rem / DIM) % DIM;  stride = DIM; }
    else              { c = rem % DIM;          stride = 1; }
    float acc = 0.f;
    #pragma unroll
    for (int t = -9; t <= 9; ++t) {
        const int cc = c + t;
        if (cc >= 0 && cc < DIM) acc += GW[t < 0 ? -t : t] * src[id + t*stride];
    }
    dst[id] = acc;
}

// ---------------------------------------------------------------------------
// [1,2,1]/4 blur along grid axis AX (0..3), zero-padded. Operates on CH=12
// padded channels (padding stays zero).
// ---------------------------------------------------------------------------
template<int AX>
__global__ __launch_bounds__(256)
void k_blur(const float* __restrict__ src, float* __restrict__ dst)
{
    const int id = blockIdx.x * 256 + threadIdx.x;
    if (id >= GRIDF) return;
    const int cell = id / CH;
    int c, ext, stride;
    if (AX == 0)      { c = cell / ST0;         ext = GD0; stride = ST0; }
    else if (AX == 1) { c = (cell / ST1) % GD1; ext = GD1; stride = ST1; }
    else if (AX == 2) { c = (cell / ST2) % GD2; ext = GD2; stride = ST2; }
    else              { c = cell % GD3;         ext = GD3; stride = 1; }
    const float mid = src[id];
    const float a = (c > 0)       ? src[id - stride*CH] : 0.f;
    const float b = (c < ext - 1) ? src[id + stride*CH] : 0.f;
    dst[id] = 0.25f*a + 0.5f*mid + 0.25f*b;
}

// ---------------------------------------------------------------------------
// CS = C@S, CB = C@B  (8x8 each) -> mats[0..63], mats[64..127]
// ---------------------------------------------------------------------------
__global__ void k_matprep(const float* __restrict__ Cm, const float* __restrict__ Sm,
                          const float* __restrict__ Bm, float* __restrict__ mats)
{
    const int t = threadIdx.x;
    if (t < 64) {
        const int i = t >> 3, j = t & 7;
        float cs = 0.f, cb = 0.f;
        for (int k = 0; k < 8; ++k) {
            cs += Cm[i*8 + k] * Sm[k*8 + j];
            cb += Cm[i*8 + k] * Bm[k*8 + j];
        }
        mats[t] = cs;
        mats[64 + t] = cb;
    }
}

// ---------------------------------------------------------------------------
// Final: slice bilateral grid, normalize, Qp = CS@sp + CB@bi,
// out = softmax(U + Qp). Reads sp from d_out (own indices) then overwrites.
// ---------------------------------------------------------------------------
__global__ __launch_bounds__(256)
void k_final(const float* __restrict__ U, const float* __restrict__ img,
             const float* sp, const float* __restrict__ grid,
             const float* __restrict__ mats, float* out)
{
    __shared__ float sm[128];
    if (threadIdx.x < 128) sm[threadIdx.x] = mats[threadIdx.x];
    __syncthreads();

    const int vox = blockIdx.x * 256 + threadIdx.x;
    if (vox >= NVOX) return;
    const int z = vox / PLANE;
    const int y = (vox / DIM) % DIM;
    const int x = vox % DIM;
    const int lz = z >> 3, lyc = y >> 3, lxc = x >> 3;
    const float fz = (float)(z & 7) * 0.125f;
    const float fy = (float)(y & 7) * 0.125f;
    const float fx = (float)(x & 7) * 0.125f;
    const float f = img[vox] * 8.0f;
    int li = (int)floorf(f);
    li = li < 0 ? 0 : (li > 8 ? 8 : li);
    const float fi = f - (float)li;
    const float wz[2]  = {1.f - fz, fz};
    const float wyv[2] = {1.f - fy, fy};
    const float wxv[2] = {1.f - fx, fx};
    const float wiv[2] = {1.f - fi, fi};

    float acc[9];
    #pragma unroll
    for (int c = 0; c < 9; ++c) acc[c] = 0.f;

    #pragma unroll
    for (int i2 = 0; i2 < 2; ++i2)
    #pragma unroll
    for (int j2 = 0; j2 < 2; ++j2)
    #pragma unroll
    for (int k2 = 0; k2 < 2; ++k2) {
        const float wsp = wz[i2] * wyv[j2] * wxv[k2];
        const int cellbase = (lz+i2)*ST0 + (lyc+j2)*ST1 + (lxc+k2)*ST2 + li;
        #pragma unroll
        for (int m2 = 0; m2 < 2; ++m2) {
            const float w = wsp * wiv[m2];
            const float* p = &grid[(cellbase + m2) * CH];
            const float4 p0 = *reinterpret_cast<const float4*>(p);
            const float4 p1 = *reinterpret_cast<const float4*>(p + 4);
            acc[0] += w * p0.x; acc[1] += w * p0.y; acc[2] += w * p0.z; acc[3] += w * p0.w;
            acc[4] += w * p1.x; acc[5] += w * p1.y; acc[6] += w * p1.z; acc[7] += w * p1.w;
            acc[8] += w * p[8];
        }
    }
    const float dinv = 1.f / (acc[8] + 1e-8f);
    float bi[8], spv[8], u[8];
    #pragma unroll
    for (int l = 0; l < 8; ++l) {
        bi[l]  = acc[l] * dinv;
        spv[l] = sp[l*NVOX + vox];
        u[l]   = U[l*NVOX + vox];
    }
    float v[8];
    float mx = -1e30f;
    #pragma unroll
    for (int i = 0; i < 8; ++i) {
        float t = 0.f;
        #pragma unroll
        for (int l = 0; l < 8; ++l) t += sm[i*8 + l] * spv[l] + sm[64 + i*8 + l] * bi[l];
        v[i] = u[i] + t;
        mx = fmaxf(mx, v[i]);
    }
    float ssum = 0.f;
    #pragma unroll
    for (int i = 0; i < 8; ++i) { v[i] = expf(v[i] - mx); ssum += v[i]; }
    const float inv = 1.f / ssum;
    #pragma unroll
    for (int i = 0; i < 8; ++i) out[i*NVOX + vox] = v[i] * inv;
}

extern "C" void kernel_launch(void* const* d_in, const int* in_sizes, int n_in,
                              void* d_out, int out_size, void* d_ws, size_t ws_size,
                              hipStream_t stream)
{
    const float* U   = (const float*)d_in[0];
    const float* img = (const float*)d_in[1];
    const float* Sw  = (const float*)d_in[2];
    const float* Bw  = (const float*)d_in[3];
    const float* Cm  = (const float*)d_in[4];
    float* out = (float*)d_out;
    float* ws  = (float*)d_ws;

    float* q     = ws;                          // 7077888 floats
    float* gridA = ws + (size_t)LBL * NVOX;     // 329280 floats
    float* gridB = gridA + GRIDF;               // 329280 floats
    float* mats  = gridB + GRIDF;               // 128 floats

    hipMemsetAsync(gridA, 0, GRIDF * sizeof(float), stream);
    k_matprep<<<1, 64, 0, stream>>>(Cm, Sw, Bw, mats);

    k_softmax_splat<<<1728, 512, 0, stream>>>(U, img, q, gridA);

    const int gth = LBL * NVOX;
    k_gauss<2><<<(gth + 255)/256, 256, 0, stream>>>(q,   out);  // x
    k_gauss<1><<<(gth + 255)/256, 256, 0, stream>>>(out, q);    // y
    k_gauss<0><<<(gth + 255)/256, 256, 0, stream>>>(q,   out);  // z -> sp in out

    k_blur<0><<<(GRIDF + 255)/256, 256, 0, stream>>>(gridA, gridB);
    k_blur<1><<<(GRIDF + 255)/256, 256, 0, stream>>>(gridB, gridA);
    k_blur<2><<<(GRIDF + 255)/256, 256, 0, stream>>>(gridA, gridB);
    k_blur<3><<<(GRIDF + 255)/256, 256, 0, stream>>>(gridB, gridA);

    k_final<<<(NVOX + 255)/256, 256, 0, stream>>>(U, img, out, gridA, mats, out);
}

// Round 3
// 304.594 us; speedup vs baseline: 3.0936x; 3.0936x over previous
//
#include <hip/hip_runtime.h>
#include <math.h>

#define LBL   8
#define DIM   96
#define PLANE (DIM*DIM)          // 9216
#define NVOX  (DIM*DIM*DIM)      // 884736
#define GD0 14
#define GD1 14
#define GD2 14
#define GD3 10
#define GSIZE (GD0*GD1*GD2*GD3)  // 27440
#define ST0 1960
#define ST1 140
#define ST2 10
#define CH  12                   // padded channel stride (9 used)
#define NBLK 12
#define NBLKS (NBLK*NBLK*NBLK)   // 1728
#define PART 720                 // per-block partial size: 8 corners x 10 bins x 9 ch
#define GOUT (GSIZE*9)           // 246960 real grid scalars

// normalized Gaussian weights, sigma=3, radius=9 (by |t|)
__constant__ float GW[10] = {
    0.13317604f, 0.12597912f, 0.10663904f, 0.08077540f, 0.05475300f,
    0.03320771f, 0.01802341f, 0.00875346f, 0.00380423f, 0.00147945f
};

// ---------------------------------------------------------------------------
// Kernel A: per-voxel softmax + 4-D bilateral-grid splat, NO ATOMICS.
// Block = 8x8x8 voxels. HW model from R0/R1: LDS atomics cost ~3.3 cy/lane
// serially -> replaced by a 3-stage owned separable reduction:
//   stage A: x-reduce  -> sA[row(64)][k2(2)][g(10)][c(9)]
//   stage B: y-reduce  -> sB[lz(8)][j2(2)][k2(2)][g(10)][c(9)]
//   stage C: z-reduce  -> part[block][corner(8)][g(10)][c(9)]   (global write)
// Intensity tent weight: w(g) = max(0, 1-|f-g|), f = img*8 (exact).
// ---------------------------------------------------------------------------
__global__ __launch_bounds__(512)
void k_softmax_splat(const float* __restrict__ U, const float* __restrict__ img,
                     float* __restrict__ q, float* __restrict__ part)
{
    __shared__ float sF[512];
    __shared__ float sU[9*512];
    __shared__ float sA[64*180];   // row*180 + k2*90 + g*9 + c
    __shared__ float sB[8*360];    // lz*360 + j2*180 + k2*90 + g*9 + c

    const int tid = threadIdx.x;
    const int bid = blockIdx.x;
    const int bx = bid % NBLK;
    const int by = (bid / NBLK) % NBLK;
    const int bz = bid / (NBLK*NBLK);

    const int lx = tid & 7;
    const int ly = (tid >> 3) & 7;
    const int lz = tid >> 6;

    const int x = bx*8 + lx;
    const int y = by*8 + ly;
    const int z = bz*8 + lz;
    const int vox = z * PLANE + y * DIM + x;

    // ---- phase 0: softmax, write q, stage voxel data in LDS ----
    {
        float u[LBL];
        float m = -1e30f;
        #pragma unroll
        for (int l = 0; l < LBL; ++l) { u[l] = U[l*NVOX + vox]; m = fmaxf(m, u[l]); }
        float ssum = 0.f;
        #pragma unroll
        for (int l = 0; l < LBL; ++l) { u[l] = expf(u[l] - m); ssum += u[l]; }
        const float inv = 1.f / ssum;
        #pragma unroll
        for (int l = 0; l < LBL; ++l) {
            u[l] *= inv;
            q[l*NVOX + vox] = u[l];
            sU[l*512 + tid] = u[l];
        }
        sU[8*512 + tid] = 1.0f;        // homogeneous channel
        sF[tid] = img[vox] * 8.0f;     // f = img/BETA, in [0,8); li+fi == f exactly
    }
    __syncthreads();

    // ---- stage A: x-reduce. thread = (row, k2, cgrp) ----
    {
        const int cgrp = tid & 3;          // ch groups {0,1},{2,3},{4,5},{6,7,8}
        const int k2   = (tid >> 2) & 1;
        const int row  = tid >> 3;         // 0..63  (ly + 8*lz)
        const int cb   = cgrp * 2;

        float bins[10][3];
        #pragma unroll
        for (int g = 0; g < 10; ++g) { bins[g][0]=0.f; bins[g][1]=0.f; bins[g][2]=0.f; }

        for (int vx = 0; vx < 8; ++vx) {
            const int vi = row*8 + vx;
            const float f  = sF[vi];
            const float wx = k2 ? (float)vx*0.125f : 1.f - (float)vx*0.125f;
            const float u0 = sU[cb*512 + vi];
            const float u1 = sU[(cb+1)*512 + vi];
            const float u2 = sU[8*512 + vi];   // only meaningful for cgrp==3
            #pragma unroll
            for (int g = 0; g < 10; ++g) {
                float w = fmaxf(1.f - fabsf(f - (float)g), 0.f) * wx;
                bins[g][0] += w*u0; bins[g][1] += w*u1; bins[g][2] += w*u2;
            }
        }
        float* pA = sA + row*180 + k2*90;
        #pragma unroll
        for (int g = 0; g < 10; ++g) {
            pA[g*9 + cb]     = bins[g][0];
            pA[g*9 + cb + 1] = bins[g][1];
            if (cgrp == 3) pA[g*9 + 8] = bins[g][2];
        }
    }
    __syncthreads();

    // ---- stage B: y-reduce. thread = (lz, j2, k2, c), 288 active ----
    if (tid < 288) {
        const int c   = tid % 9;
        const int k2  = (tid / 9) & 1;
        const int j2  = (tid / 18) & 1;
        const int lzo = tid / 36;          // 0..7
        float S[10];
        #pragma unroll
        for (int g = 0; g < 10; ++g) S[g] = 0.f;
        for (int ly2 = 0; ly2 < 8; ++ly2) {
            const float wy = j2 ? (float)ly2*0.125f : 1.f - (float)ly2*0.125f;
            const float* pA = sA + (lzo*8 + ly2)*180 + k2*90;
            #pragma unroll
            for (int g = 0; g < 10; ++g) S[g] += wy * pA[g*9 + c];
        }
        float* pB = sB + lzo*360 + j2*180 + k2*90;
        #pragma unroll
        for (int g = 0; g < 10; ++g) pB[g*9 + c] = S[g];
    }
    __syncthreads();

    // ---- stage C: z-reduce -> global partial (no atomics) ----
    for (int item = tid; item < PART; item += 512) {
        const int t  = item / 90;          // corner: i2*4 + j2*2 + k2
        const int gc = item % 90;
        const int i2 = t >> 2, j2 = (t >> 1) & 1, k2 = t & 1;
        float acc = 0.f;
        #pragma unroll
        for (int lzo = 0; lzo < 8; ++lzo) {
            const float wz = i2 ? (float)lzo*0.125f : 1.f - (float)lzo*0.125f;
            acc += wz * sB[lzo*360 + j2*180 + k2*90 + gc];
        }
        part[(size_t)bid*PART + item] = acc;
    }
}

// ---------------------------------------------------------------------------
// Gather per-cell partials from the <=8 contributing blocks (deterministic).
// ---------------------------------------------------------------------------
__global__ __launch_bounds__(256)
void k_reduce(const float* __restrict__ part, float* __restrict__ grid)
{
    const int item = blockIdx.x*256 + threadIdx.x;
    if (item >= GOUT) return;
    const int c    = item % 9;
    const int cell = item / 9;
    const int gz = cell / ST0;
    int r = cell % ST0;
    const int gy = r / ST1;  r %= ST1;
    const int gx = r / ST2;
    const int g  = r % ST2;
    float acc = 0.f;
    #pragma unroll
    for (int t = 0; t < 8; ++t) {
        const int i2 = t >> 2, j2 = (t >> 1) & 1, k2 = t & 1;
        const int bz = gz - i2, by = gy - j2, bx = gx - k2;
        if ((unsigned)bz < (unsigned)NBLK && (unsigned)by < (unsigned)NBLK &&
            (unsigned)bx < (unsigned)NBLK)
            acc += part[(size_t)((bz*NBLK + by)*NBLK + bx)*PART + t*90 + g*9 + c];
    }
    grid[cell*CH + c] = acc;
}

// ---------------------------------------------------------------------------
// Separable 19-tap Gaussian along axis AX (0=z,1=y,2=x), zero-padded.
// ---------------------------------------------------------------------------
template<int AX>
__global__ __launch_bounds__(256)
void k_gauss(const float* __restrict__ src, float* __restrict__ dst)
{
    const int id = blockIdx.x * 256 + threadIdx.x;
    if (id >= LBL * NVOX) return;
    const int rem = id % NVOX;
    int c, stride;
    if (AX == 0)      { c = rem / PLANE;        stride = PLANE; }
    else if (AX == 1) { c = (rem / DIM) % DIM;  stride = DIM; }
    else              { c = rem % DIM;          stride = 1; }
    float acc = 0.f;
    #pragma unroll
    for (int t = -9; t <= 9; ++t) {
        const int cc = c + t;
        if (cc >= 0 && cc < DIM) acc += GW[t < 0 ? -t : t] * src[id + t*stride];
    }
    dst[id] = acc;
}

// ---------------------------------------------------------------------------
// Fused [1,2,1]/4 blur over TWO grid axes (PAIR 0: z,y; PAIR 1: x,intensity).
// 9-tap 2-D stencil, zero-padded; only the 9 real channels are processed.
// ---------------------------------------------------------------------------
template<int PAIR>
__global__ __launch_bounds__(256)
void k_blur2(const float* __restrict__ src, float* __restrict__ dst)
{
    const int item = blockIdx.x*256 + threadIdx.x;
    if (item >= GOUT) return;
    const int c    = item % 9;
    const int cell = item / 9;
    const int gz = cell / ST0;
    int r = cell % ST0;
    const int gy = r / ST1;  r %= ST1;
    const int gx = r / ST2;
    const int g  = r % ST2;
    int ca, cb, ea, eb, sa, sb;
    if (PAIR == 0) { ca = gz; ea = GD0; sa = ST0; cb = gy; eb = GD1; sb = ST1; }
    else           { ca = gx; ea = GD2; sa = ST2; cb = g;  eb = GD3; sb = 1;  }
    float acc = 0.f;
    #pragma unroll
    for (int da = -1; da <= 1; ++da) {
        const int a = ca + da;
        if (a < 0 || a >= ea) continue;
        const float wa = (da == 0) ? 0.5f : 0.25f;
        #pragma unroll
        for (int db = -1; db <= 1; ++db) {
            const int b = cb + db;
            if (b < 0 || b >= eb) continue;
            const float wb = (db == 0) ? 0.5f : 0.25f;
            acc += wa * wb * src[(cell + da*sa + db*sb)*CH + c];
        }
    }
    dst[cell*CH + c] = acc;
}

// ---------------------------------------------------------------------------
// CS = C@S, CB = C@B  (8x8 each) -> mats[0..63], mats[64..127]
// ---------------------------------------------------------------------------
__global__ void k_matprep(const float* __restrict__ Cm, const float* __restrict__ Sm,
                          const float* __restrict__ Bm, float* __restrict__ mats)
{
    const int t = threadIdx.x;
    if (t < 64) {
        const int i = t >> 3, j = t & 7;
        float cs = 0.f, cb = 0.f;
        for (int k = 0; k < 8; ++k) {
            cs += Cm[i*8 + k] * Sm[k*8 + j];
            cb += Cm[i*8 + k] * Bm[k*8 + j];
        }
        mats[t] = cs;
        mats[64 + t] = cb;
    }
}

// ---------------------------------------------------------------------------
// Final: slice bilateral grid, normalize, Qp = CS@sp + CB@bi,
// out = softmax(U + Qp). Reads sp from d_out (own indices) then overwrites.
// ---------------------------------------------------------------------------
__global__ __launch_bounds__(256)
void k_final(const float* __restrict__ U, const float* __restrict__ img,
             const float* sp, const float* __restrict__ grid,
             const float* __restrict__ mats, float* out)
{
    __shared__ float sm[128];
    if (threadIdx.x < 128) sm[threadIdx.x] = mats[threadIdx.x];
    __syncthreads();

    const int vox = blockIdx.x * 256 + threadIdx.x;
    if (vox >= NVOX) return;
    const int z = vox / PLANE;
    const int y = (vox / DIM) % DIM;
    const int x = vox % DIM;
    const int lz = z >> 3, lyc = y >> 3, lxc = x >> 3;
    const float fz = (float)(z & 7) * 0.125f;
    const float fy = (float)(y & 7) * 0.125f;
    const float fx = (float)(x & 7) * 0.125f;
    const float f = img[vox] * 8.0f;
    int li = (int)floorf(f);
    li = li < 0 ? 0 : (li > 8 ? 8 : li);
    const float fi = f - (float)li;
    const float wz[2]  = {1.f - fz, fz};
    const float wyv[2] = {1.f - fy, fy};
    const float wxv[2] = {1.f - fx, fx};
    const float wiv[2] = {1.f - fi, fi};

    float acc[9];
    #pragma unroll
    for (int c = 0; c < 9; ++c) acc[c] = 0.f;

    #pragma unroll
    for (int i2 = 0; i2 < 2; ++i2)
    #pragma unroll
    for (int j2 = 0; j2 < 2; ++j2)
    #pragma unroll
    for (int k2 = 0; k2 < 2; ++k2) {
        const float wsp = wz[i2] * wyv[j2] * wxv[k2];
        const int cellbase = (lz+i2)*ST0 + (lyc+j2)*ST1 + (lxc+k2)*ST2 + li;
        #pragma unroll
        for (int m2 = 0; m2 < 2; ++m2) {
            const float w = wsp * wiv[m2];
            const float* p = &grid[(cellbase + m2) * CH];
            const float4 p0 = *reinterpret_cast<const float4*>(p);
            const float4 p1 = *reinterpret_cast<const float4*>(p + 4);
            acc[0] += w * p0.x; acc[1] += w * p0.y; acc[2] += w * p0.z; acc[3] += w * p0.w;
            acc[4] += w * p1.x; acc[5] += w * p1.y; acc[6] += w * p1.z; acc[7] += w * p1.w;
            acc[8] += w * p[8];
        }
    }
    const float dinv = 1.f / (acc[8] + 1e-8f);
    float bi[8], spv[8], u[8];
    #pragma unroll
    for (int l = 0; l < 8; ++l) {
        bi[l]  = acc[l] * dinv;
        spv[l] = sp[l*NVOX + vox];
        u[l]   = U[l*NVOX + vox];
    }
    float v[8];
    float mx = -1e30f;
    #pragma unroll
    for (int i = 0; i < 8; ++i) {
        float t = 0.f;
        #pragma unroll
        for (int l = 0; l < 8; ++l) t += sm[i*8 + l] * spv[l] + sm[64 + i*8 + l] * bi[l];
        v[i] = u[i] + t;
        mx = fmaxf(mx, v[i]);
    }
    float ssum = 0.f;
    #pragma unroll
    for (int i = 0; i < 8; ++i) { v[i] = expf(v[i] - mx); ssum += v[i]; }
    const float inv = 1.f / ssum;
    #pragma unroll
    for (int i = 0; i < 8; ++i) out[i*NVOX + vox] = v[i] * inv;
}

extern "C" void kernel_launch(void* const* d_in, const int* in_sizes, int n_in,
                              void* d_out, int out_size, void* d_ws, size_t ws_size,
                              hipStream_t stream)
{
    const float* U   = (const float*)d_in[0];
    const float* img = (const float*)d_in[1];
    const float* Sw  = (const float*)d_in[2];
    const float* Bw  = (const float*)d_in[3];
    const float* Cm  = (const float*)d_in[4];
    float* out = (float*)d_out;
    float* ws  = (float*)d_ws;

    float* q     = ws;                             // 7,077,888 floats
    float* gridA = q + (size_t)LBL * NVOX;         // 329,280 floats
    float* part  = gridA + (size_t)GSIZE * CH;     // 1,244,160 floats
    float* gridB = part;                           // aliases part (dead after k_reduce)
    float* mats  = part + (size_t)NBLKS * PART;    // 128 floats

    k_matprep<<<1, 64, 0, stream>>>(Cm, Sw, Bw, mats);

    k_softmax_splat<<<NBLKS, 512, 0, stream>>>(U, img, q, part);
    k_reduce<<<(GOUT + 255)/256, 256, 0, stream>>>(part, gridA);

    const int gth = LBL * NVOX;
    k_gauss<2><<<(gth + 255)/256, 256, 0, stream>>>(q,   out);  // x
    k_gauss<1><<<(gth + 255)/256, 256, 0, stream>>>(out, q);    // y
    k_gauss<0><<<(gth + 255)/256, 256, 0, stream>>>(q,   out);  // z -> sp in out

    k_blur2<0><<<(GOUT + 255)/256, 256, 0, stream>>>(gridA, gridB); // z,y
    k_blur2<1><<<(GOUT + 255)/256, 256, 0, stream>>>(gridB, gridA); // x,intensity

    k_final<<<(NVOX + 255)/256, 256, 0, stream>>>(U, img, out, gridA, mats, out);
}

// Round 4
// 154.987 us; speedup vs baseline: 6.0797x; 1.9653x over previous
//
#include <hip/hip_runtime.h>
#include <math.h>

#define LBL   8
#define DIM   96
#define PLANE (DIM*DIM)          // 9216
#define NVOX  (DIM*DIM*DIM)      // 884736
#define GD0 14
#define GD1 14
#define GD2 14
#define GD3 10
#define GSIZE (GD0*GD1*GD2*GD3)  // 27440
#define ST0 1960
#define ST1 140
#define ST2 10
#define CH  12                   // padded channel stride (9 used)
#define NBLK 12
#define NBLKS (NBLK*NBLK*NBLK)   // 1728
#define PART 720                 // per-block partial size: 8 corners x 10 bins x 9 ch
#define GOUT (GSIZE*9)           // 246960 real grid scalars
#define ROW4 (DIM/4)             // 24 float4 per row
#define NV4  (LBL*NVOX/4)        // 1769472 float4 items
#define GAUSS_BLKS (NV4/256)     // 6912 (divisible by 8)

// normalized Gaussian weights, sigma=3, radius=9 (by |t|)
__constant__ float GW[10] = {
    0.13317604f, 0.12597912f, 0.10663904f, 0.08077540f, 0.05475300f,
    0.03320771f, 0.01802341f, 0.00875346f, 0.00380423f, 0.00147945f
};

// ---------------------------------------------------------------------------
// Kernel A: per-voxel softmax + 4-D bilateral-grid splat, NO ATOMICS.
// (unchanged from R2 — 3-stage owned separable reduction)
// ---------------------------------------------------------------------------
__global__ __launch_bounds__(512)
void k_softmax_splat(const float* __restrict__ U, const float* __restrict__ img,
                     float* __restrict__ q, float* __restrict__ part)
{
    __shared__ float sF[512];
    __shared__ float sU[9*512];
    __shared__ float sA[64*180];   // row*180 + k2*90 + g*9 + c
    __shared__ float sB[8*360];    // lz*360 + j2*180 + k2*90 + g*9 + c

    const int tid = threadIdx.x;
    const int bid = blockIdx.x;
    const int bx = bid % NBLK;
    const int by = (bid / NBLK) % NBLK;
    const int bz = bid / (NBLK*NBLK);

    const int lx = tid & 7;
    const int ly = (tid >> 3) & 7;
    const int lz = tid >> 6;

    const int x = bx*8 + lx;
    const int y = by*8 + ly;
    const int z = bz*8 + lz;
    const int vox = z * PLANE + y * DIM + x;

    // ---- phase 0: softmax, write q, stage voxel data in LDS ----
    {
        float u[LBL];
        float m = -1e30f;
        #pragma unroll
        for (int l = 0; l < LBL; ++l) { u[l] = U[l*NVOX + vox]; m = fmaxf(m, u[l]); }
        float ssum = 0.f;
        #pragma unroll
        for (int l = 0; l < LBL; ++l) { u[l] = expf(u[l] - m); ssum += u[l]; }
        const float inv = 1.f / ssum;
        #pragma unroll
        for (int l = 0; l < LBL; ++l) {
            u[l] *= inv;
            q[l*NVOX + vox] = u[l];
            sU[l*512 + tid] = u[l];
        }
        sU[8*512 + tid] = 1.0f;        // homogeneous channel
        sF[tid] = img[vox] * 8.0f;     // f = img/BETA, in [0,8); li+fi == f exactly
    }
    __syncthreads();

    // ---- stage A: x-reduce. thread = (row, k2, cgrp) ----
    {
        const int cgrp = tid & 3;          // ch groups {0,1},{2,3},{4,5},{6,7,8}
        const int k2   = (tid >> 2) & 1;
        const int row  = tid >> 3;         // 0..63  (ly + 8*lz)
        const int cb   = cgrp * 2;

        float bins[10][3];
        #pragma unroll
        for (int g = 0; g < 10; ++g) { bins[g][0]=0.f; bins[g][1]=0.f; bins[g][2]=0.f; }

        for (int vx = 0; vx < 8; ++vx) {
            const int vi = row*8 + vx;
            const float f  = sF[vi];
            const float wx = k2 ? (float)vx*0.125f : 1.f - (float)vx*0.125f;
            const float u0 = sU[cb*512 + vi];
            const float u1 = sU[(cb+1)*512 + vi];
            const float u2 = sU[8*512 + vi];   // only meaningful for cgrp==3
            #pragma unroll
            for (int g = 0; g < 10; ++g) {
                float w = fmaxf(1.f - fabsf(f - (float)g), 0.f) * wx;
                bins[g][0] += w*u0; bins[g][1] += w*u1; bins[g][2] += w*u2;
            }
        }
        float* pA = sA + row*180 + k2*90;
        #pragma unroll
        for (int g = 0; g < 10; ++g) {
            pA[g*9 + cb]     = bins[g][0];
            pA[g*9 + cb + 1] = bins[g][1];
            if (cgrp == 3) pA[g*9 + 8] = bins[g][2];
        }
    }
    __syncthreads();

    // ---- stage B: y-reduce. thread = (lz, j2, k2, c), 288 active ----
    if (tid < 288) {
        const int c   = tid % 9;
        const int k2  = (tid / 9) & 1;
        const int j2  = (tid / 18) & 1;
        const int lzo = tid / 36;          // 0..7
        float S[10];
        #pragma unroll
        for (int g = 0; g < 10; ++g) S[g] = 0.f;
        for (int ly2 = 0; ly2 < 8; ++ly2) {
            const float wy = j2 ? (float)ly2*0.125f : 1.f - (float)ly2*0.125f;
            const float* pA = sA + (lzo*8 + ly2)*180 + k2*90;
            #pragma unroll
            for (int g = 0; g < 10; ++g) S[g] += wy * pA[g*9 + c];
        }
        float* pB = sB + lzo*360 + j2*180 + k2*90;
        #pragma unroll
        for (int g = 0; g < 10; ++g) pB[g*9 + c] = S[g];
    }
    __syncthreads();

    // ---- stage C: z-reduce -> global partial (no atomics) ----
    for (int item = tid; item < PART; item += 512) {
        const int t  = item / 90;          // corner: i2*4 + j2*2 + k2
        const int gc = item % 90;
        const int i2 = t >> 2, j2 = (t >> 1) & 1, k2 = t & 1;
        float acc = 0.f;
        #pragma unroll
        for (int lzo = 0; lzo < 8; ++lzo) {
            const float wz = i2 ? (float)lzo*0.125f : 1.f - (float)lzo*0.125f;
            acc += wz * sB[lzo*360 + j2*180 + k2*90 + gc];
        }
        part[(size_t)bid*PART + item] = acc;
    }
}

// ---------------------------------------------------------------------------
// Gather per-cell partials from the <=8 contributing blocks (deterministic).
// ---------------------------------------------------------------------------
__global__ __launch_bounds__(256)
void k_reduce(const float* __restrict__ part, float* __restrict__ grid)
{
    const int item = blockIdx.x*256 + threadIdx.x;
    if (item >= GOUT) return;
    const int c    = item % 9;
    const int cell = item / 9;
    const int gz = cell / ST0;
    int r = cell % ST0;
    const int gy = r / ST1;  r %= ST1;
    const int gx = r / ST2;
    const int g  = r % ST2;
    float acc = 0.f;
    #pragma unroll
    for (int t = 0; t < 8; ++t) {
        const int i2 = t >> 2, j2 = (t >> 1) & 1, k2 = t & 1;
        const int bz = gz - i2, by = gy - j2, bx = gx - k2;
        if ((unsigned)bz < (unsigned)NBLK && (unsigned)by < (unsigned)NBLK &&
            (unsigned)bx < (unsigned)NBLK)
            acc += part[(size_t)((bz*NBLK + by)*NBLK + bx)*PART + t*90 + g*9 + c];
    }
    grid[cell*CH + c] = acc;
}

// ---------------------------------------------------------------------------
// Separable 19-tap Gaussian, float4-vectorized (4 x-consecutive outputs per
// thread) + XCD-chunk block swizzle (neighbor blocks share an XCD's L2).
// AX: 0=z, 1=y, 2=x. Zero-padded.
// ---------------------------------------------------------------------------
template<int AX>
__global__ __launch_bounds__(256)
void k_gauss(const float* __restrict__ src, float* __restrict__ dst)
{
    const int cpx = GAUSS_BLKS >> 3;
    const int bid = blockIdx.x;
    const int swz = (bid & 7) * cpx + (bid >> 3);
    const int id4 = swz * 256 + threadIdx.x;   // float4 item, grid covers exactly NV4

    const float4* __restrict__ s4 = reinterpret_cast<const float4*>(src);
    float4*       __restrict__ d4 = reinterpret_cast<float4*>(dst);

    if (AX == 2) {
        const int x4 = id4 % ROW4;
        const float4* row = s4 + (id4 - x4);
        float va[28];
        #pragma unroll
        for (int k = 0; k < 7; ++k) {
            const int j = x4 + k - 3;
            float4 v;
            if (j >= 0 && j < ROW4) v = row[j];
            else { v.x = 0.f; v.y = 0.f; v.z = 0.f; v.w = 0.f; }
            va[k*4+0] = v.x; va[k*4+1] = v.y; va[k*4+2] = v.z; va[k*4+3] = v.w;
        }
        float o0 = 0.f, o1 = 0.f, o2 = 0.f, o3 = 0.f;
        #pragma unroll
        for (int t = -9; t <= 9; ++t) {
            const float w = GW[t < 0 ? -t : t];
            o0 += w * va[12 + 0 + t];
            o1 += w * va[12 + 1 + t];
            o2 += w * va[12 + 2 + t];
            o3 += w * va[12 + 3 + t];
        }
        float4 o; o.x = o0; o.y = o1; o.z = o2; o.w = o3;
        d4[id4] = o;
    } else {
        int c, stride4;
        if (AX == 1) { c = (id4 / ROW4) % DIM;         stride4 = ROW4; }
        else         { c = (id4 / (ROW4*DIM)) % DIM;   stride4 = ROW4*DIM; }
        float4 acc; acc.x = 0.f; acc.y = 0.f; acc.z = 0.f; acc.w = 0.f;
        #pragma unroll
        for (int t = -9; t <= 9; ++t) {
            const int cc = c + t;
            if (cc >= 0 && cc < DIM) {
                const float w = GW[t < 0 ? -t : t];
                const float4 v = s4[id4 + t*stride4];
                acc.x += w*v.x; acc.y += w*v.y; acc.z += w*v.z; acc.w += w*v.w;
            }
        }
        d4[id4] = acc;
    }
}

// ---------------------------------------------------------------------------
// Fused [1,2,1]/4 blur over TWO grid axes (PAIR 0: z,y; PAIR 1: x,intensity).
// ---------------------------------------------------------------------------
template<int PAIR>
__global__ __launch_bounds__(256)
void k_blur2(const float* __restrict__ src, float* __restrict__ dst)
{
    const int item = blockIdx.x*256 + threadIdx.x;
    if (item >= GOUT) return;
    const int c    = item % 9;
    const int cell = item / 9;
    const int gz = cell / ST0;
    int r = cell % ST0;
    const int gy = r / ST1;  r %= ST1;
    const int gx = r / ST2;
    const int g  = r % ST2;
    int ca, cb, ea, eb, sa, sb;
    if (PAIR == 0) { ca = gz; ea = GD0; sa = ST0; cb = gy; eb = GD1; sb = ST1; }
    else           { ca = gx; ea = GD2; sa = ST2; cb = g;  eb = GD3; sb = 1;  }
    float acc = 0.f;
    #pragma unroll
    for (int da = -1; da <= 1; ++da) {
        const int a = ca + da;
        if (a < 0 || a >= ea) continue;
        const float wa = (da == 0) ? 0.5f : 0.25f;
        #pragma unroll
        for (int db = -1; db <= 1; ++db) {
            const int b = cb + db;
            if (b < 0 || b >= eb) continue;
            const float wb = (db == 0) ? 0.5f : 0.25f;
            acc += wa * wb * src[(cell + da*sa + db*sb)*CH + c];
        }
    }
    dst[cell*CH + c] = acc;
}

// ---------------------------------------------------------------------------
// CS = C@S, CB = C@B  (8x8 each) -> mats[0..63], mats[64..127]
// ---------------------------------------------------------------------------
__global__ void k_matprep(const float* __restrict__ Cm, const float* __restrict__ Sm,
                          const float* __restrict__ Bm, float* __restrict__ mats)
{
    const int t = threadIdx.x;
    if (t < 64) {
        const int i = t >> 3, j = t & 7;
        float cs = 0.f, cb = 0.f;
        for (int k = 0; k < 8; ++k) {
            cs += Cm[i*8 + k] * Sm[k*8 + j];
            cb += Cm[i*8 + k] * Bm[k*8 + j];
        }
        mats[t] = cs;
        mats[64 + t] = cb;
    }
}

// ---------------------------------------------------------------------------
// Final: slice bilateral grid, normalize, Qp = CS@sp + CB@bi,
// out = softmax(U + Qp). Reads sp from d_out (own indices) then overwrites.
// ---------------------------------------------------------------------------
__global__ __launch_bounds__(256)
void k_final(const float* __restrict__ U, const float* __restrict__ img,
             const float* sp, const float* __restrict__ grid,
             const float* __restrict__ mats, float* out)
{
    __shared__ float sm[128];
    if (threadIdx.x < 128) sm[threadIdx.x] = mats[threadIdx.x];
    __syncthreads();

    const int vox = blockIdx.x * 256 + threadIdx.x;
    if (vox >= NVOX) return;
    const int z = vox / PLANE;
    const int y = (vox / DIM) % DIM;
    const int x = vox % DIM;
    const int lz = z >> 3, lyc = y >> 3, lxc = x >> 3;
    const float fz = (float)(z & 7) * 0.125f;
    const float fy = (float)(y & 7) * 0.125f;
    const float fx = (float)(x & 7) * 0.125f;
    const float f = img[vox] * 8.0f;
    int li = (int)floorf(f);
    li = li < 0 ? 0 : (li > 8 ? 8 : li);
    const float fi = f - (float)li;
    const float wz[2]  = {1.f - fz, fz};
    const float wyv[2] = {1.f - fy, fy};
    const float wxv[2] = {1.f - fx, fx};
    const float wiv[2] = {1.f - fi, fi};

    float acc[9];
    #pragma unroll
    for (int c = 0; c < 9; ++c) acc[c] = 0.f;

    #pragma unroll
    for (int i2 = 0; i2 < 2; ++i2)
    #pragma unroll
    for (int j2 = 0; j2 < 2; ++j2)
    #pragma unroll
    for (int k2 = 0; k2 < 2; ++k2) {
        const float wsp = wz[i2] * wyv[j2] * wxv[k2];
        const int cellbase = (lz+i2)*ST0 + (lyc+j2)*ST1 + (lxc+k2)*ST2 + li;
        #pragma unroll
        for (int m2 = 0; m2 < 2; ++m2) {
            const float w = wsp * wiv[m2];
            const float* p = &grid[(cellbase + m2) * CH];
            const float4 p0 = *reinterpret_cast<const float4*>(p);
            const float4 p1 = *reinterpret_cast<const float4*>(p + 4);
            acc[0] += w * p0.x; acc[1] += w * p0.y; acc[2] += w * p0.z; acc[3] += w * p0.w;
            acc[4] += w * p1.x; acc[5] += w * p1.y; acc[6] += w * p1.z; acc[7] += w * p1.w;
            acc[8] += w * p[8];
        }
    }
    const float dinv = 1.f / (acc[8] + 1e-8f);
    float bi[8], spv[8], u[8];
    #pragma unroll
    for (int l = 0; l < 8; ++l) {
        bi[l]  = acc[l] * dinv;
        spv[l] = sp[l*NVOX + vox];
        u[l]   = U[l*NVOX + vox];
    }
    float v[8];
    float mx = -1e30f;
    #pragma unroll
    for (int i = 0; i < 8; ++i) {
        float t = 0.f;
        #pragma unroll
        for (int l = 0; l < 8; ++l) t += sm[i*8 + l] * spv[l] + sm[64 + i*8 + l] * bi[l];
        v[i] = u[i] + t;
        mx = fmaxf(mx, v[i]);
    }
    float ssum = 0.f;
    #pragma unroll
    for (int i = 0; i < 8; ++i) { v[i] = expf(v[i] - mx); ssum += v[i]; }
    const float inv = 1.f / ssum;
    #pragma unroll
    for (int i = 0; i < 8; ++i) out[i*NVOX + vox] = v[i] * inv;
}

extern "C" void kernel_launch(void* const* d_in, const int* in_sizes, int n_in,
                              void* d_out, int out_size, void* d_ws, size_t ws_size,
                              hipStream_t stream)
{
    const float* U   = (const float*)d_in[0];
    const float* img = (const float*)d_in[1];
    const float* Sw  = (const float*)d_in[2];
    const float* Bw  = (const float*)d_in[3];
    const float* Cm  = (const float*)d_in[4];
    float* out = (float*)d_out;
    float* ws  = (float*)d_ws;

    float* q     = ws;                             // 7,077,888 floats
    float* gridA = q + (size_t)LBL * NVOX;         // 329,280 floats
    float* part  = gridA + (size_t)GSIZE * CH;     // 1,244,160 floats
    float* gridB = part;                           // aliases part (dead after k_reduce)
    float* mats  = part + (size_t)NBLKS * PART;    // 128 floats

    k_matprep<<<1, 64, 0, stream>>>(Cm, Sw, Bw, mats);

    k_softmax_splat<<<NBLKS, 512, 0, stream>>>(U, img, q, part);
    k_reduce<<<(GOUT + 255)/256, 256, 0, stream>>>(part, gridA);

    k_gauss<2><<<GAUSS_BLKS, 256, 0, stream>>>(q,   out);  // x
    k_gauss<1><<<GAUSS_BLKS, 256, 0, stream>>>(out, q);    // y
    k_gauss<0><<<GAUSS_BLKS, 256, 0, stream>>>(q,   out);  // z -> sp in out

    k_blur2<0><<<(GOUT + 255)/256, 256, 0, stream>>>(gridA, gridB); // z,y
    k_blur2<1><<<(GOUT + 255)/256, 256, 0, stream>>>(gridB, gridA); // x,intensity

    k_final<<<(NVOX + 255)/256, 256, 0, stream>>>(U, img, out, gridA, mats, out);
}

// Round 5
// 141.571 us; speedup vs baseline: 6.6559x; 1.0948x over previous
//
#include <hip/hip_runtime.h>
#include <math.h>

#define LBL   8
#define DIM   96
#define PLANE (DIM*DIM)          // 9216
#define NVOX  (DIM*DIM*DIM)      // 884736
#define GD0 14
#define GD1 14
#define GD2 14
#define GD3 10
#define GSIZE (GD0*GD1*GD2*GD3)  // 27440
#define ST0 1960
#define ST1 140
#define ST2 10
#define CH  12                   // padded channel stride (9 used)
#define NBLK 12
#define NBLKS (NBLK*NBLK*NBLK)   // 1728
#define PART 720                 // per-block partial size: 8 corners x 10 bins x 9 ch
#define GOUT (GSIZE*9)           // 246960 real grid scalars
#define ROW4 (DIM/4)             // 24 float4 per row
#define NV4  (LBL*NVOX/4)        // 1769472 float4 items
#define GAUSS_BLKS (NV4/256)     // 6912 (divisible by 8)
#define SUP 513                  // padded sU stride (bank-conflict fix)

// normalized Gaussian weights, sigma=3, radius=9 (by |t|)
__constant__ float GW[10] = {
    0.13317604f, 0.12597912f, 0.10663904f, 0.08077540f, 0.05475300f,
    0.03320771f, 0.01802341f, 0.00875346f, 0.00380423f, 0.00147945f
};

// ---------------------------------------------------------------------------
// Kernel A: per-voxel softmax + 4-D bilateral-grid splat, NO ATOMICS.
// R4: XCD-chunked block swizzle (bx-neighbors share one XCD's L2 -> the
// second 32B half of each 64B line becomes an L2 hit) + sU stride 513
// (cgrp lanes land on distinct banks; was 4-way same-bank at stride 512).
// ---------------------------------------------------------------------------
__global__ __launch_bounds__(512)
void k_softmax_splat(const float* __restrict__ U, const float* __restrict__ img,
                     float* __restrict__ q, float* __restrict__ part)
{
    __shared__ float sF[512];
    __shared__ float sU[9*SUP];
    __shared__ float sA[64*180];   // row*180 + k2*90 + g*9 + c
    __shared__ float sB[8*360];    // lz*360 + j2*180 + k2*90 + g*9 + c

    const int tid = threadIdx.x;
    const int bid0 = blockIdx.x;
    const int bid = (bid0 & 7) * (NBLKS >> 3) + (bid0 >> 3);  // XCD-chunk swizzle
    const int bx = bid % NBLK;
    const int by = (bid / NBLK) % NBLK;
    const int bz = bid / (NBLK*NBLK);

    const int lx = tid & 7;
    const int ly = (tid >> 3) & 7;
    const int lz = tid >> 6;

    const int x = bx*8 + lx;
    const int y = by*8 + ly;
    const int z = bz*8 + lz;
    const int vox = z * PLANE + y * DIM + x;

    // ---- phase 0: softmax, write q, stage voxel data in LDS ----
    {
        float u[LBL];
        float m = -1e30f;
        #pragma unroll
        for (int l = 0; l < LBL; ++l) { u[l] = U[l*NVOX + vox]; m = fmaxf(m, u[l]); }
        float ssum = 0.f;
        #pragma unroll
        for (int l = 0; l < LBL; ++l) { u[l] = expf(u[l] - m); ssum += u[l]; }
        const float inv = 1.f / ssum;
        #pragma unroll
        for (int l = 0; l < LBL; ++l) {
            u[l] *= inv;
            q[l*NVOX + vox] = u[l];
            sU[l*SUP + tid] = u[l];
        }
        sU[8*SUP + tid] = 1.0f;        // homogeneous channel
        sF[tid] = img[vox] * 8.0f;     // f = img/BETA, in [0,8); li+fi == f exactly
    }
    __syncthreads();

    // ---- stage A: x-reduce. thread = (row, k2, cgrp) ----
    {
        const int cgrp = tid & 3;          // ch groups {0,1},{2,3},{4,5},{6,7,8}
        const int k2   = (tid >> 2) & 1;
        const int row  = tid >> 3;         // 0..63  (ly + 8*lz)
        const int cb   = cgrp * 2;

        float bins[10][3];
        #pragma unroll
        for (int g = 0; g < 10; ++g) { bins[g][0]=0.f; bins[g][1]=0.f; bins[g][2]=0.f; }

        for (int vx = 0; vx < 8; ++vx) {
            const int vi = row*8 + vx;
            const float f  = sF[vi];
            const float wx = k2 ? (float)vx*0.125f : 1.f - (float)vx*0.125f;
            const float u0 = sU[cb*SUP + vi];
            const float u1 = sU[(cb+1)*SUP + vi];
            const float u2 = sU[8*SUP + vi];   // only meaningful for cgrp==3
            #pragma unroll
            for (int g = 0; g < 10; ++g) {
                float w = fmaxf(1.f - fabsf(f - (float)g), 0.f) * wx;
                bins[g][0] += w*u0; bins[g][1] += w*u1; bins[g][2] += w*u2;
            }
        }
        float* pA = sA + row*180 + k2*90;
        #pragma unroll
        for (int g = 0; g < 10; ++g) {
            pA[g*9 + cb]     = bins[g][0];
            pA[g*9 + cb + 1] = bins[g][1];
            if (cgrp == 3) pA[g*9 + 8] = bins[g][2];
        }
    }
    __syncthreads();

    // ---- stage B: y-reduce. thread = (lz, j2, k2, c), 288 active ----
    if (tid < 288) {
        const int c   = tid % 9;
        const int k2  = (tid / 9) & 1;
        const int j2  = (tid / 18) & 1;
        const int lzo = tid / 36;          // 0..7
        float S[10];
        #pragma unroll
        for (int g = 0; g < 10; ++g) S[g] = 0.f;
        for (int ly2 = 0; ly2 < 8; ++ly2) {
            const float wy = j2 ? (float)ly2*0.125f : 1.f - (float)ly2*0.125f;
            const float* pA = sA + (lzo*8 + ly2)*180 + k2*90;
            #pragma unroll
            for (int g = 0; g < 10; ++g) S[g] += wy * pA[g*9 + c];
        }
        float* pB = sB + lzo*360 + j2*180 + k2*90;
        #pragma unroll
        for (int g = 0; g < 10; ++g) pB[g*9 + c] = S[g];
    }
    __syncthreads();

    // ---- stage C: z-reduce -> global partial (no atomics) ----
    for (int item = tid; item < PART; item += 512) {
        const int t  = item / 90;          // corner: i2*4 + j2*2 + k2
        const int gc = item % 90;
        const int i2 = t >> 2, j2 = (t >> 1) & 1, k2 = t & 1;
        float acc = 0.f;
        #pragma unroll
        for (int lzo = 0; lzo < 8; ++lzo) {
            const float wz = i2 ? (float)lzo*0.125f : 1.f - (float)lzo*0.125f;
            acc += wz * sB[lzo*360 + j2*180 + k2*90 + gc];
        }
        part[(size_t)bid*PART + item] = acc;
    }
}

// ---------------------------------------------------------------------------
// Gather per-cell partials from the <=8 contributing blocks (deterministic).
// ---------------------------------------------------------------------------
__global__ __launch_bounds__(256)
void k_reduce(const float* __restrict__ part, float* __restrict__ grid)
{
    const int item = blockIdx.x*256 + threadIdx.x;
    if (item >= GOUT) return;
    const int c    = item % 9;
    const int cell = item / 9;
    const int gz = cell / ST0;
    int r = cell % ST0;
    const int gy = r / ST1;  r %= ST1;
    const int gx = r / ST2;
    const int g  = r % ST2;
    float acc = 0.f;
    #pragma unroll
    for (int t = 0; t < 8; ++t) {
        const int i2 = t >> 2, j2 = (t >> 1) & 1, k2 = t & 1;
        const int bz = gz - i2, by = gy - j2, bx = gx - k2;
        if ((unsigned)bz < (unsigned)NBLK && (unsigned)by < (unsigned)NBLK &&
            (unsigned)bx < (unsigned)NBLK)
            acc += part[(size_t)((bz*NBLK + by)*NBLK + bx)*PART + t*90 + g*9 + c];
    }
    grid[cell*CH + c] = acc;
}

// ---------------------------------------------------------------------------
// Separable 19-tap Gaussian, float4-vectorized (4 x-consecutive outputs per
// thread) + XCD-chunk block swizzle (neighbor blocks share an XCD's L2).
// AX: 0=z, 1=y, 2=x. Zero-padded.
// ---------------------------------------------------------------------------
template<int AX>
__global__ __launch_bounds__(256)
void k_gauss(const float* __restrict__ src, float* __restrict__ dst)
{
    const int cpx = GAUSS_BLKS >> 3;
    const int bid = blockIdx.x;
    const int swz = (bid & 7) * cpx + (bid >> 3);
    const int id4 = swz * 256 + threadIdx.x;   // float4 item, grid covers exactly NV4

    const float4* __restrict__ s4 = reinterpret_cast<const float4*>(src);
    float4*       __restrict__ d4 = reinterpret_cast<float4*>(dst);

    if (AX == 2) {
        const int x4 = id4 % ROW4;
        const float4* row = s4 + (id4 - x4);
        float va[28];
        #pragma unroll
        for (int k = 0; k < 7; ++k) {
            const int j = x4 + k - 3;
            float4 v;
            if (j >= 0 && j < ROW4) v = row[j];
            else { v.x = 0.f; v.y = 0.f; v.z = 0.f; v.w = 0.f; }
            va[k*4+0] = v.x; va[k*4+1] = v.y; va[k*4+2] = v.z; va[k*4+3] = v.w;
        }
        float o0 = 0.f, o1 = 0.f, o2 = 0.f, o3 = 0.f;
        #pragma unroll
        for (int t = -9; t <= 9; ++t) {
            const float w = GW[t < 0 ? -t : t];
            o0 += w * va[12 + 0 + t];
            o1 += w * va[12 + 1 + t];
            o2 += w * va[12 + 2 + t];
            o3 += w * va[12 + 3 + t];
        }
        float4 o; o.x = o0; o.y = o1; o.z = o2; o.w = o3;
        d4[id4] = o;
    } else {
        int c, stride4;
        if (AX == 1) { c = (id4 / ROW4) % DIM;         stride4 = ROW4; }
        else         { c = (id4 / (ROW4*DIM)) % DIM;   stride4 = ROW4*DIM; }
        float4 acc; acc.x = 0.f; acc.y = 0.f; acc.z = 0.f; acc.w = 0.f;
        #pragma unroll
        for (int t = -9; t <= 9; ++t) {
            const int cc = c + t;
            if (cc >= 0 && cc < DIM) {
                const float w = GW[t < 0 ? -t : t];
                const float4 v = s4[id4 + t*stride4];
                acc.x += w*v.x; acc.y += w*v.y; acc.z += w*v.z; acc.w += w*v.w;
            }
        }
        d4[id4] = acc;
    }
}

// ---------------------------------------------------------------------------
// Fused [1,2,1]/4 blur over TWO grid axes (PAIR 0: z,y; PAIR 1: x,intensity).
// ---------------------------------------------------------------------------
template<int PAIR>
__global__ __launch_bounds__(256)
void k_blur2(const float* __restrict__ src, float* __restrict__ dst)
{
    const int item = blockIdx.x*256 + threadIdx.x;
    if (item >= GOUT) return;
    const int c    = item % 9;
    const int cell = item / 9;
    const int gz = cell / ST0;
    int r = cell % ST0;
    const int gy = r / ST1;  r %= ST1;
    const int gx = r / ST2;
    const int g  = r % ST2;
    int ca, cb, ea, eb, sa, sb;
    if (PAIR == 0) { ca = gz; ea = GD0; sa = ST0; cb = gy; eb = GD1; sb = ST1; }
    else           { ca = gx; ea = GD2; sa = ST2; cb = g;  eb = GD3; sb = 1;  }
    float acc = 0.f;
    #pragma unroll
    for (int da = -1; da <= 1; ++da) {
        const int a = ca + da;
        if (a < 0 || a >= ea) continue;
        const float wa = (da == 0) ? 0.5f : 0.25f;
        #pragma unroll
        for (int db = -1; db <= 1; ++db) {
            const int b = cb + db;
            if (b < 0 || b >= eb) continue;
            const float wb = (db == 0) ? 0.5f : 0.25f;
            acc += wa * wb * src[(cell + da*sa + db*sb)*CH + c];
        }
    }
    dst[cell*CH + c] = acc;
}

// ---------------------------------------------------------------------------
// Final: inline CS=C@S, CB=C@B (first 64 lanes), slice bilateral grid,
// normalize, Qp = CS@sp + CB@bi, out = softmax(U + Qp).
// Reads sp from d_out (own indices) then overwrites.
// ---------------------------------------------------------------------------
__global__ __launch_bounds__(256)
void k_final(const float* __restrict__ U, const float* __restrict__ img,
             const float* sp, const float* __restrict__ grid,
             const float* __restrict__ Cm, const float* __restrict__ Sw,
             const float* __restrict__ Bw, float* out)
{
    __shared__ float sm[128];
    if (threadIdx.x < 64) {
        const int i = threadIdx.x >> 3, j = threadIdx.x & 7;
        float cs = 0.f, cb = 0.f;
        #pragma unroll
        for (int k = 0; k < 8; ++k) {
            cs += Cm[i*8 + k] * Sw[k*8 + j];
            cb += Cm[i*8 + k] * Bw[k*8 + j];
        }
        sm[threadIdx.x] = cs;
        sm[64 + threadIdx.x] = cb;
    }
    __syncthreads();

    const int vox = blockIdx.x * 256 + threadIdx.x;
    if (vox >= NVOX) return;
    const int z = vox / PLANE;
    const int y = (vox / DIM) % DIM;
    const int x = vox % DIM;
    const int lz = z >> 3, lyc = y >> 3, lxc = x >> 3;
    const float fz = (float)(z & 7) * 0.125f;
    const float fy = (float)(y & 7) * 0.125f;
    const float fx = (float)(x & 7) * 0.125f;
    const float f = img[vox] * 8.0f;
    int li = (int)floorf(f);
    li = li < 0 ? 0 : (li > 8 ? 8 : li);
    const float fi = f - (float)li;
    const float wz[2]  = {1.f - fz, fz};
    const float wyv[2] = {1.f - fy, fy};
    const float wxv[2] = {1.f - fx, fx};
    const float wiv[2] = {1.f - fi, fi};

    float acc[9];
    #pragma unroll
    for (int c = 0; c < 9; ++c) acc[c] = 0.f;

    #pragma unroll
    for (int i2 = 0; i2 < 2; ++i2)
    #pragma unroll
    for (int j2 = 0; j2 < 2; ++j2)
    #pragma unroll
    for (int k2 = 0; k2 < 2; ++k2) {
        const float wsp = wz[i2] * wyv[j2] * wxv[k2];
        const int cellbase = (lz+i2)*ST0 + (lyc+j2)*ST1 + (lxc+k2)*ST2 + li;
        #pragma unroll
        for (int m2 = 0; m2 < 2; ++m2) {
            const float w = wsp * wiv[m2];
            const float* p = &grid[(cellbase + m2) * CH];
            const float4 p0 = *reinterpret_cast<const float4*>(p);
            const float4 p1 = *reinterpret_cast<const float4*>(p + 4);
            acc[0] += w * p0.x; acc[1] += w * p0.y; acc[2] += w * p0.z; acc[3] += w * p0.w;
            acc[4] += w * p1.x; acc[5] += w * p1.y; acc[6] += w * p1.z; acc[7] += w * p1.w;
            acc[8] += w * p[8];
        }
    }
    const float dinv = 1.f / (acc[8] + 1e-8f);
    float bi[8], spv[8], u[8];
    #pragma unroll
    for (int l = 0; l < 8; ++l) {
        bi[l]  = acc[l] * dinv;
        spv[l] = sp[l*NVOX + vox];
        u[l]   = U[l*NVOX + vox];
    }
    float v[8];
    float mx = -1e30f;
    #pragma unroll
    for (int i = 0; i < 8; ++i) {
        float t = 0.f;
        #pragma unroll
        for (int l = 0; l < 8; ++l) t += sm[i*8 + l] * spv[l] + sm[64 + i*8 + l] * bi[l];
        v[i] = u[i] + t;
        mx = fmaxf(mx, v[i]);
    }
    float ssum = 0.f;
    #pragma unroll
    for (int i = 0; i < 8; ++i) { v[i] = expf(v[i] - mx); ssum += v[i]; }
    const float inv = 1.f / ssum;
    #pragma unroll
    for (int i = 0; i < 8; ++i) out[i*NVOX + vox] = v[i] * inv;
}

extern "C" void kernel_launch(void* const* d_in, const int* in_sizes, int n_in,
                              void* d_out, int out_size, void* d_ws, size_t ws_size,
                              hipStream_t stream)
{
    const float* U   = (const float*)d_in[0];
    const float* img = (const float*)d_in[1];
    const float* Sw  = (const float*)d_in[2];
    const float* Bw  = (const float*)d_in[3];
    const float* Cm  = (const float*)d_in[4];
    float* out = (float*)d_out;
    float* ws  = (float*)d_ws;

    float* q     = ws;                             // 7,077,888 floats
    float* gridA = q + (size_t)LBL * NVOX;         // 329,280 floats
    float* part  = gridA + (size_t)GSIZE * CH;     // 1,244,160 floats
    float* gridB = part;                           // aliases part (dead after k_reduce)

    k_softmax_splat<<<NBLKS, 512, 0, stream>>>(U, img, q, part);
    k_reduce<<<(GOUT + 255)/256, 256, 0, stream>>>(part, gridA);

    k_gauss<2><<<GAUSS_BLKS, 256, 0, stream>>>(q,   out);  // x
    k_gauss<1><<<GAUSS_BLKS, 256, 0, stream>>>(out, q);    // y
    k_gauss<0><<<GAUSS_BLKS, 256, 0, stream>>>(q,   out);  // z -> sp in out

    k_blur2<0><<<(GOUT + 255)/256, 256, 0, stream>>>(gridA, gridB); // z,y
    k_blur2<1><<<(GOUT + 255)/256, 256, 0, stream>>>(gridB, gridA); // x,intensity

    k_final<<<(NVOX + 255)/256, 256, 0, stream>>>(U, img, out, gridA, Cm, Sw, Bw, out);
}

// Round 6
// 106.818 us; speedup vs baseline: 8.8213x; 1.3253x over previous
//
#include <hip/hip_runtime.h>
#include <math.h>

#define LBL   8
#define DIM   96
#define PLANE (DIM*DIM)          // 9216
#define NVOX  (DIM*DIM*DIM)      // 884736
#define GD0 14
#define GD1 14
#define GD2 14
#define GD3 10
#define GSIZE (GD0*GD1*GD2*GD3)  // 27440
#define ST0 1960
#define ST1 140
#define ST2 10
#define CH  12                   // padded channel stride (9 used)
#define NBLK 12
#define NBLKS (NBLK*NBLK*NBLK)   // 1728
#define PART 720                 // per-block partial size: 8 corners x 10 bins x 9 ch
#define GOUT (GSIZE*9)           // 246960 real grid scalars
#define SUP 513                  // padded sU stride (bank-conflict fix)
#define ROW8 (DIM/8)             // 12 half8 per row
#define PLANE8 (PLANE/8)         // 1152 half8 per z-slice
#define VOL8 (NVOX/8)            // 110592 half8 per label

typedef _Float16 half8 __attribute__((ext_vector_type(8)));

__device__ inline half8 h8zero() {
    half8 v;
    #pragma unroll
    for (int e = 0; e < 8; ++e) v[e] = (_Float16)0.f;
    return v;
}

// normalized Gaussian weights, sigma=3, radius=9 (by |t|)
__constant__ float GW[10] = {
    0.13317604f, 0.12597912f, 0.10663904f, 0.08077540f, 0.05475300f,
    0.03320771f, 0.01802341f, 0.00875346f, 0.00380423f, 0.00147945f
};

// ---------------------------------------------------------------------------
// Kernel A: per-voxel softmax + 4-D bilateral-grid splat, NO ATOMICS.
// (R4 structure; q now stored as fp16 — halves the q write traffic.)
// ---------------------------------------------------------------------------
__global__ __launch_bounds__(512)
void k_softmax_splat(const float* __restrict__ U, const float* __restrict__ img,
                     _Float16* __restrict__ q, float* __restrict__ part)
{
    __shared__ float sF[512];
    __shared__ float sU[9*SUP];
    __shared__ float sA[64*180];   // row*180 + k2*90 + g*9 + c
    __shared__ float sB[8*360];    // lz*360 + j2*180 + k2*90 + g*9 + c

    const int tid = threadIdx.x;
    const int bid0 = blockIdx.x;
    const int bid = (bid0 & 7) * (NBLKS >> 3) + (bid0 >> 3);  // XCD-chunk swizzle
    const int bx = bid % NBLK;
    const int by = (bid / NBLK) % NBLK;
    const int bz = bid / (NBLK*NBLK);

    const int lx = tid & 7;
    const int ly = (tid >> 3) & 7;
    const int lz = tid >> 6;

    const int x = bx*8 + lx;
    const int y = by*8 + ly;
    const int z = bz*8 + lz;
    const int vox = z * PLANE + y * DIM + x;

    // ---- phase 0: softmax, write q (fp16), stage voxel data in LDS ----
    {
        float u[LBL];
        float m = -1e30f;
        #pragma unroll
        for (int l = 0; l < LBL; ++l) { u[l] = U[l*NVOX + vox]; m = fmaxf(m, u[l]); }
        float ssum = 0.f;
        #pragma unroll
        for (int l = 0; l < LBL; ++l) { u[l] = expf(u[l] - m); ssum += u[l]; }
        const float inv = 1.f / ssum;
        #pragma unroll
        for (int l = 0; l < LBL; ++l) {
            u[l] *= inv;
            q[l*NVOX + vox] = (_Float16)u[l];
            sU[l*SUP + tid] = u[l];
        }
        sU[8*SUP + tid] = 1.0f;        // homogeneous channel
        sF[tid] = img[vox] * 8.0f;     // f = img/BETA, in [0,8); li+fi == f exactly
    }
    __syncthreads();

    // ---- stage A: x-reduce. thread = (row, k2, cgrp) ----
    {
        const int cgrp = tid & 3;          // ch groups {0,1},{2,3},{4,5},{6,7,8}
        const int k2   = (tid >> 2) & 1;
        const int row  = tid >> 3;         // 0..63  (ly + 8*lz)
        const int cb   = cgrp * 2;

        float bins[10][3];
        #pragma unroll
        for (int g = 0; g < 10; ++g) { bins[g][0]=0.f; bins[g][1]=0.f; bins[g][2]=0.f; }

        for (int vx = 0; vx < 8; ++vx) {
            const int vi = row*8 + vx;
            const float f  = sF[vi];
            const float wx = k2 ? (float)vx*0.125f : 1.f - (float)vx*0.125f;
            const float u0 = sU[cb*SUP + vi];
            const float u1 = sU[(cb+1)*SUP + vi];
            const float u2 = sU[8*SUP + vi];   // only meaningful for cgrp==3
            #pragma unroll
            for (int g = 0; g < 10; ++g) {
                float w = fmaxf(1.f - fabsf(f - (float)g), 0.f) * wx;
                bins[g][0] += w*u0; bins[g][1] += w*u1; bins[g][2] += w*u2;
            }
        }
        float* pA = sA + row*180 + k2*90;
        #pragma unroll
        for (int g = 0; g < 10; ++g) {
            pA[g*9 + cb]     = bins[g][0];
            pA[g*9 + cb + 1] = bins[g][1];
            if (cgrp == 3) pA[g*9 + 8] = bins[g][2];
        }
    }
    __syncthreads();

    // ---- stage B: y-reduce. thread = (lz, j2, k2, c), 288 active ----
    if (tid < 288) {
        const int c   = tid % 9;
        const int k2  = (tid / 9) & 1;
        const int j2  = (tid / 18) & 1;
        const int lzo = tid / 36;          // 0..7
        float S[10];
        #pragma unroll
        for (int g = 0; g < 10; ++g) S[g] = 0.f;
        for (int ly2 = 0; ly2 < 8; ++ly2) {
            const float wy = j2 ? (float)ly2*0.125f : 1.f - (float)ly2*0.125f;
            const float* pA = sA + (lzo*8 + ly2)*180 + k2*90;
            #pragma unroll
            for (int g = 0; g < 10; ++g) S[g] += wy * pA[g*9 + c];
        }
        float* pB = sB + lzo*360 + j2*180 + k2*90;
        #pragma unroll
        for (int g = 0; g < 10; ++g) pB[g*9 + c] = S[g];
    }
    __syncthreads();

    // ---- stage C: z-reduce -> global partial (no atomics) ----
    for (int item = tid; item < PART; item += 512) {
        const int t  = item / 90;          // corner: i2*4 + j2*2 + k2
        const int gc = item % 90;
        const int i2 = t >> 2, j2 = (t >> 1) & 1, k2 = t & 1;
        float acc = 0.f;
        #pragma unroll
        for (int lzo = 0; lzo < 8; ++lzo) {
            const float wz = i2 ? (float)lzo*0.125f : 1.f - (float)lzo*0.125f;
            acc += wz * sB[lzo*360 + j2*180 + k2*90 + gc];
        }
        part[(size_t)bid*PART + item] = acc;
    }
}

// ---------------------------------------------------------------------------
// Gather per-cell partials from the <=8 contributing blocks (deterministic).
// ---------------------------------------------------------------------------
__global__ __launch_bounds__(256)
void k_reduce(const float* __restrict__ part, float* __restrict__ grid)
{
    const int item = blockIdx.x*256 + threadIdx.x;
    if (item >= GOUT) return;
    const int c    = item % 9;
    const int cell = item / 9;
    const int gz = cell / ST0;
    int r = cell % ST0;
    const int gy = r / ST1;  r %= ST1;
    const int gx = r / ST2;
    const int g  = r % ST2;
    float acc = 0.f;
    #pragma unroll
    for (int t = 0; t < 8; ++t) {
        const int i2 = t >> 2, j2 = (t >> 1) & 1, k2 = t & 1;
        const int bz = gz - i2, by = gy - j2, bx = gx - k2;
        if ((unsigned)bz < (unsigned)NBLK && (unsigned)by < (unsigned)NBLK &&
            (unsigned)bx < (unsigned)NBLK)
            acc += part[(size_t)((bz*NBLK + by)*NBLK + bx)*PART + t*90 + g*9 + c];
    }
    grid[cell*CH + c] = acc;
}

// ---------------------------------------------------------------------------
// Gaussian x-pass, fp16 io. Thread owns 16 consecutive x (2 half8 out),
// loads the 6 aligned half8 covering its 48-half window.
// Grid: 442368 units / 256 = 1728 blocks (XCD-chunk swizzled).
// ---------------------------------------------------------------------------
__global__ __launch_bounds__(256)
void k_gauss_x(const half8* __restrict__ src, half8* __restrict__ dst)
{
    const int bid = blockIdx.x;
    const int swz = (bid & 7) * (1728 >> 3) + (bid >> 3);
    const int u = swz * 256 + threadIdx.x;
    const int xu = u % 6;          // 16-wide x segment within row
    const int row = u / 6;         // (l,z,y) row id
    const int rb8 = row * ROW8;

    float w[48];                   // x = 16*xu - 16 + k
    #pragma unroll
    for (int k = 0; k < 6; ++k) {
        const int j8 = 2*xu - 2 + k;
        half8 v = h8zero();
        if (j8 >= 0 && j8 < ROW8) v = src[rb8 + j8];
        #pragma unroll
        for (int e = 0; e < 8; ++e) w[k*8 + e] = (float)v[e];
    }
    half8 o0 = h8zero(), o1 = h8zero();
    #pragma unroll
    for (int i = 0; i < 16; ++i) {
        float acc = 0.f;
        #pragma unroll
        for (int t = -9; t <= 9; ++t) acc += GW[t < 0 ? -t : t] * w[i + 16 + t];
        if (i < 8) o0[i] = (_Float16)acc; else o1[i - 8] = (_Float16)acc;
    }
    dst[rb8 + 2*xu]     = o0;
    dst[rb8 + 2*xu + 1] = o1;
}

// ---------------------------------------------------------------------------
// Gaussian y/z-pass, fp16 io. Thread owns 8 x-halves x 4 outputs along the
// blur axis (22 tap loads for 4 outputs -> cache tap traffic / 3.45).
// AX: 0=z, 1=y. Grid: 221184 units / 256 = 864 blocks (swizzled).
// ---------------------------------------------------------------------------
template<int AX>
__global__ __launch_bounds__(256)
void k_gauss_yz(const half8* __restrict__ src, half8* __restrict__ dst)
{
    const int bid = blockIdx.x;
    const int swz = (bid & 7) * (864 >> 3) + (bid >> 3);
    const int u = swz * 256 + threadIdx.x;

    const int x8 = u % ROW8;
    int base8, ct, stride8;
    if (AX == 1) {                      // y axis
        const int yt = (u / ROW8) % (DIM/4);
        const int zl = u / (ROW8 * (DIM/4));    // (l*96+z)
        base8 = zl * PLANE8 + x8;
        ct = yt * 4;
        stride8 = ROW8;
    } else {                            // z axis
        const int yy = (u / ROW8) % DIM;
        const int ztl = u / (ROW8 * DIM);       // zt + 24*l
        const int zt = ztl % (DIM/4);
        const int l  = ztl / (DIM/4);
        base8 = l * VOL8 + yy * ROW8 + x8;
        ct = zt * 4;
        stride8 = PLANE8;
    }

    float acc[4][8];
    #pragma unroll
    for (int k = 0; k < 4; ++k)
        #pragma unroll
        for (int e = 0; e < 8; ++e) acc[k][e] = 0.f;

    #pragma unroll
    for (int jj = 0; jj < 22; ++jj) {
        const int j = ct - 9 + jj;
        if (j < 0 || j >= DIM) continue;
        const half8 v = src[base8 + j*stride8];
        float f[8];
        #pragma unroll
        for (int e = 0; e < 8; ++e) f[e] = (float)v[e];
        #pragma unroll
        for (int k = 0; k < 4; ++k) {
            const int d = jj - 9 - k;           // = j - (ct+k)
            if (d >= -9 && d <= 9) {
                const float wgt = GW[d < 0 ? -d : d];
                #pragma unroll
                for (int e = 0; e < 8; ++e) acc[k][e] += wgt * f[e];
            }
        }
    }
    #pragma unroll
    for (int k = 0; k < 4; ++k) {
        half8 o;
        #pragma unroll
        for (int e = 0; e < 8; ++e) o[e] = (_Float16)acc[k][e];
        dst[base8 + (ct + k)*stride8] = o;
    }
}

// ---------------------------------------------------------------------------
// Fused 4-axis [1,2,1]/4 blur: one 81-tap kernel (grid is L2-resident).
// OOB taps get weight 0 (offset clamped to 0 so loads stay in range).
// ---------------------------------------------------------------------------
__global__ __launch_bounds__(256)
void k_blur81(const float* __restrict__ src, float* __restrict__ dst)
{
    const int item = blockIdx.x*256 + threadIdx.x;
    if (item >= GOUT) return;
    const int c    = item % 9;
    const int cell = item / 9;
    const int gz = cell / ST0;
    int r = cell % ST0;
    const int gy = r / ST1;  r %= ST1;
    const int gx = r / ST2;
    const int g  = r % ST2;

    const int crd[4] = {gz, gy, gx, g};
    const int ext[4] = {GD0, GD1, GD2, GD3};
    const int str[4] = {ST0, ST1, ST2, 1};
    float wa[4][3];
    int   oa[4][3];
    #pragma unroll
    for (int ax = 0; ax < 4; ++ax)
        #pragma unroll
        for (int dd = 0; dd < 3; ++dd) {
            const int cc = crd[ax] + dd - 1;
            const bool ok = (cc >= 0 && cc < ext[ax]);
            wa[ax][dd] = ok ? (dd == 1 ? 0.5f : 0.25f) : 0.f;
            oa[ax][dd] = ok ? (dd - 1) * str[ax] : 0;
        }

    float acc = 0.f;
    #pragma unroll
    for (int a = 0; a < 3; ++a) {
        const float w0 = wa[0][a];
        #pragma unroll
        for (int b = 0; b < 3; ++b) {
            const float w1 = w0 * wa[1][b];
            #pragma unroll
            for (int d2 = 0; d2 < 3; ++d2) {
                const float w2 = w1 * wa[2][d2];
                const int ob = oa[0][a] + oa[1][b] + oa[2][d2];
                #pragma unroll
                for (int e = 0; e < 3; ++e)
                    acc += w2 * wa[3][e] * src[(cell + ob + oa[3][e])*CH + c];
            }
        }
    }
    dst[cell*CH + c] = acc;
}

// ---------------------------------------------------------------------------
// Final: inline CS=C@S, CB=C@B, slice bilateral grid, normalize,
// Qp = CS@sp + CB@bi, out = softmax(U + Qp). sp is fp16.
// ---------------------------------------------------------------------------
__global__ __launch_bounds__(256)
void k_final(const float* __restrict__ U, const float* __restrict__ img,
             const _Float16* __restrict__ sp, const float* __restrict__ grid,
             const float* __restrict__ Cm, const float* __restrict__ Sw,
             const float* __restrict__ Bw, float* __restrict__ out)
{
    __shared__ float sm[128];
    if (threadIdx.x < 64) {
        const int i = threadIdx.x >> 3, j = threadIdx.x & 7;
        float cs = 0.f, cb = 0.f;
        #pragma unroll
        for (int k = 0; k < 8; ++k) {
            cs += Cm[i*8 + k] * Sw[k*8 + j];
            cb += Cm[i*8 + k] * Bw[k*8 + j];
        }
        sm[threadIdx.x] = cs;
        sm[64 + threadIdx.x] = cb;
    }
    __syncthreads();

    const int vox = blockIdx.x * 256 + threadIdx.x;
    if (vox >= NVOX) return;
    const int z = vox / PLANE;
    const int y = (vox / DIM) % DIM;
    const int x = vox % DIM;
    const int lz = z >> 3, lyc = y >> 3, lxc = x >> 3;
    const float fz = (float)(z & 7) * 0.125f;
    const float fy = (float)(y & 7) * 0.125f;
    const float fx = (float)(x & 7) * 0.125f;
    const float f = img[vox] * 8.0f;
    int li = (int)floorf(f);
    li = li < 0 ? 0 : (li > 8 ? 8 : li);
    const float fi = f - (float)li;
    const float wz[2]  = {1.f - fz, fz};
    const float wyv[2] = {1.f - fy, fy};
    const float wxv[2] = {1.f - fx, fx};
    const float wiv[2] = {1.f - fi, fi};

    float acc[9];
    #pragma unroll
    for (int c = 0; c < 9; ++c) acc[c] = 0.f;

    #pragma unroll
    for (int i2 = 0; i2 < 2; ++i2)
    #pragma unroll
    for (int j2 = 0; j2 < 2; ++j2)
    #pragma unroll
    for (int k2 = 0; k2 < 2; ++k2) {
        const float wsp = wz[i2] * wyv[j2] * wxv[k2];
        const int cellbase = (lz+i2)*ST0 + (lyc+j2)*ST1 + (lxc+k2)*ST2 + li;
        #pragma unroll
        for (int m2 = 0; m2 < 2; ++m2) {
            const float w = wsp * wiv[m2];
            const float* p = &grid[(cellbase + m2) * CH];
            const float4 p0 = *reinterpret_cast<const float4*>(p);
            const float4 p1 = *reinterpret_cast<const float4*>(p + 4);
            acc[0] += w * p0.x; acc[1] += w * p0.y; acc[2] += w * p0.z; acc[3] += w * p0.w;
            acc[4] += w * p1.x; acc[5] += w * p1.y; acc[6] += w * p1.z; acc[7] += w * p1.w;
            acc[8] += w * p[8];
        }
    }
    const float dinv = 1.f / (acc[8] + 1e-8f);
    float bi[8], spv[8], uu[8];
    #pragma unroll
    for (int l = 0; l < 8; ++l) {
        bi[l]  = acc[l] * dinv;
        spv[l] = (float)sp[l*NVOX + vox];
        uu[l]  = U[l*NVOX + vox];
    }
    float v[8];
    float mx = -1e30f;
    #pragma unroll
    for (int i = 0; i < 8; ++i) {
        float t = 0.f;
        #pragma unroll
        for (int l = 0; l < 8; ++l) t += sm[i*8 + l] * spv[l] + sm[64 + i*8 + l] * bi[l];
        v[i] = uu[i] + t;
        mx = fmaxf(mx, v[i]);
    }
    float ssum = 0.f;
    #pragma unroll
    for (int i = 0; i < 8; ++i) { v[i] = expf(v[i] - mx); ssum += v[i]; }
    const float inv = 1.f / ssum;
    #pragma unroll
    for (int i = 0; i < 8; ++i) out[i*NVOX + vox] = v[i] * inv;
}

extern "C" void kernel_launch(void* const* d_in, const int* in_sizes, int n_in,
                              void* d_out, int out_size, void* d_ws, size_t ws_size,
                              hipStream_t stream)
{
    const float* U   = (const float*)d_in[0];
    const float* img = (const float*)d_in[1];
    const float* Sw  = (const float*)d_in[2];
    const float* Bw  = (const float*)d_in[3];
    const float* Cm  = (const float*)d_in[4];
    float* out = (float*)d_out;

    _Float16* qh  = (_Float16*)d_ws;                       // 8*NVOX halves
    _Float16* g1h = qh + (size_t)LBL * NVOX;               // 8*NVOX halves
    float* gridA  = (float*)(g1h + (size_t)LBL * NVOX);    // GRIDF=GSIZE*CH floats
    float* part   = gridA + (size_t)GSIZE * CH;            // NBLKS*PART floats
    float* gridB  = part;                                  // alias (dead after reduce)

    k_softmax_splat<<<NBLKS, 512, 0, stream>>>(U, img, qh, part);
    k_reduce<<<(GOUT + 255)/256, 256, 0, stream>>>(part, gridA);
    k_blur81<<<(GOUT + 255)/256, 256, 0, stream>>>(gridA, gridB);

    k_gauss_x<<<1728, 256, 0, stream>>>((const half8*)qh, (half8*)g1h);       // x: qh -> g1h
    k_gauss_yz<1><<<864, 256, 0, stream>>>((const half8*)g1h, (half8*)qh);    // y: g1h -> qh
    k_gauss_yz<0><<<864, 256, 0, stream>>>((const half8*)qh, (half8*)g1h);    // z: qh -> g1h (= sp)

    k_final<<<(NVOX + 255)/256, 256, 0, stream>>>(U, img, g1h, gridB, Cm, Sw, Bw, out);
}

// Round 7
// 105.832 us; speedup vs baseline: 8.9035x; 1.0093x over previous
//
#include <hip/hip_runtime.h>
#include <math.h>

#define LBL   8
#define DIM   96
#define PLANE (DIM*DIM)          // 9216
#define NVOX  (DIM*DIM*DIM)      // 884736
#define GD0 14
#define GD1 14
#define GD2 14
#define GD3 10
#define GSIZE (GD0*GD1*GD2*GD3)  // 27440
#define ST0 1960
#define ST1 140
#define ST2 10
#define CH  12                   // padded channel stride (9 used)
#define NBLK 12
#define NBLKS (NBLK*NBLK*NBLK)   // 1728
#define PART 720                 // per-block partial size: 8 corners x 10 bins x 9 ch
#define GOUT (GSIZE*9)           // 246960 real grid scalars
#define SUP 513                  // padded sU stride in halves (bank-conflict fix)
#define ROW8 (DIM/8)             // 12 half8 per row
#define PLANE8 (PLANE/8)         // 1152 half8 per z-slice
#define VOL8 (NVOX/8)            // 110592 half8 per label

typedef _Float16 half8 __attribute__((ext_vector_type(8)));

__device__ inline half8 h8zero() {
    half8 v;
    #pragma unroll
    for (int e = 0; e < 8; ++e) v[e] = (_Float16)0.f;
    return v;
}

// normalized Gaussian weights, sigma=3, radius=9 (by |t|)
__constant__ float GW[10] = {
    0.13317604f, 0.12597912f, 0.10663904f, 0.08077540f, 0.05475300f,
    0.03320771f, 0.01802341f, 0.00875346f, 0.00380423f, 0.00147945f
};

// ---------------------------------------------------------------------------
// Kernel A: per-voxel softmax + 4-D bilateral-grid splat, NO ATOMICS.
// R6 LDS diet: sU fp16 (9.2 KB), sA fp16 (23 KB), sB fp32 unioned onto the
// dead-after-stage-A sU region. Total ~37 KB -> 4 blocks/CU (was 77 KB -> 2).
// Stage-A sU read stays conflict-free: cgrp -> +1 bank, row -> +4 banks,
// k2 -> broadcast.
// ---------------------------------------------------------------------------
__global__ __launch_bounds__(512)
void k_softmax_splat(const float* __restrict__ U, const float* __restrict__ img,
                     _Float16* __restrict__ q, float* __restrict__ part)
{
    __shared__ float sF[512];
    __shared__ __align__(16) unsigned char uball[2880 * 4];  // max(sU 9234B, sB 11520B)
    __shared__ _Float16 sA[64*180];   // row*180 + k2*90 + g*9 + c

    _Float16* sU = (_Float16*)uball;  // [9*SUP] halves, dead after stage A
    float*    sB = (float*)uball;     // [8*360] floats, written in stage B

    const int tid = threadIdx.x;
    const int bid0 = blockIdx.x;
    const int bid = (bid0 & 7) * (NBLKS >> 3) + (bid0 >> 3);  // XCD-chunk swizzle
    const int bx = bid % NBLK;
    const int by = (bid / NBLK) % NBLK;
    const int bz = bid / (NBLK*NBLK);

    const int lx = tid & 7;
    const int ly = (tid >> 3) & 7;
    const int lz = tid >> 6;

    const int x = bx*8 + lx;
    const int y = by*8 + ly;
    const int z = bz*8 + lz;
    const int vox = z * PLANE + y * DIM + x;

    // ---- phase 0: softmax, write q (fp16), stage voxel data in LDS ----
    {
        float u[LBL];
        float m = -1e30f;
        #pragma unroll
        for (int l = 0; l < LBL; ++l) { u[l] = U[l*NVOX + vox]; m = fmaxf(m, u[l]); }
        float ssum = 0.f;
        #pragma unroll
        for (int l = 0; l < LBL; ++l) { u[l] = expf(u[l] - m); ssum += u[l]; }
        const float inv = 1.f / ssum;
        #pragma unroll
        for (int l = 0; l < LBL; ++l) {
            u[l] *= inv;
            q[l*NVOX + vox] = (_Float16)u[l];
            sU[l*SUP + tid] = (_Float16)u[l];
        }
        sU[8*SUP + tid] = (_Float16)1.0f;  // homogeneous channel
        sF[tid] = img[vox] * 8.0f;         // f = img/BETA, in [0,8)
    }
    __syncthreads();

    // ---- stage A: x-reduce. thread = (row, k2, cgrp) ----
    {
        const int cgrp = tid & 3;          // ch groups {0,1},{2,3},{4,5},{6,7,8}
        const int k2   = (tid >> 2) & 1;
        const int row  = tid >> 3;         // 0..63  (ly + 8*lz)
        const int cb   = cgrp * 2;

        float bins[10][3];
        #pragma unroll
        for (int g = 0; g < 10; ++g) { bins[g][0]=0.f; bins[g][1]=0.f; bins[g][2]=0.f; }

        for (int vx = 0; vx < 8; ++vx) {
            const int vi = row*8 + vx;
            const float f  = sF[vi];
            const float wx = k2 ? (float)vx*0.125f : 1.f - (float)vx*0.125f;
            const float u0 = (float)sU[cb*SUP + vi];
            const float u1 = (float)sU[(cb+1)*SUP + vi];
            const float u2 = (float)sU[8*SUP + vi];   // only meaningful for cgrp==3
            #pragma unroll
            for (int g = 0; g < 10; ++g) {
                float w = fmaxf(1.f - fabsf(f - (float)g), 0.f) * wx;
                bins[g][0] += w*u0; bins[g][1] += w*u1; bins[g][2] += w*u2;
            }
        }
        _Float16* pA = sA + row*180 + k2*90;
        #pragma unroll
        for (int g = 0; g < 10; ++g) {
            pA[g*9 + cb]     = (_Float16)bins[g][0];
            pA[g*9 + cb + 1] = (_Float16)bins[g][1];
            if (cgrp == 3) pA[g*9 + 8] = (_Float16)bins[g][2];
        }
    }
    __syncthreads();   // sU dead from here; sB may reuse its storage

    // ---- stage B: y-reduce. thread = (lz, j2, k2, c), 288 active ----
    if (tid < 288) {
        const int c   = tid % 9;
        const int k2  = (tid / 9) & 1;
        const int j2  = (tid / 18) & 1;
        const int lzo = tid / 36;          // 0..7
        float S[10];
        #pragma unroll
        for (int g = 0; g < 10; ++g) S[g] = 0.f;
        for (int ly2 = 0; ly2 < 8; ++ly2) {
            const float wy = j2 ? (float)ly2*0.125f : 1.f - (float)ly2*0.125f;
            const _Float16* pA = sA + (lzo*8 + ly2)*180 + k2*90;
            #pragma unroll
            for (int g = 0; g < 10; ++g) S[g] += wy * (float)pA[g*9 + c];
        }
        float* pB = sB + lzo*360 + j2*180 + k2*90;
        #pragma unroll
        for (int g = 0; g < 10; ++g) pB[g*9 + c] = S[g];
    }
    __syncthreads();

    // ---- stage C: z-reduce -> global partial (no atomics) ----
    for (int item = tid; item < PART; item += 512) {
        const int t  = item / 90;          // corner: i2*4 + j2*2 + k2
        const int gc = item % 90;
        const int i2 = t >> 2, j2 = (t >> 1) & 1, k2 = t & 1;
        float acc = 0.f;
        #pragma unroll
        for (int lzo = 0; lzo < 8; ++lzo) {
            const float wz = i2 ? (float)lzo*0.125f : 1.f - (float)lzo*0.125f;
            acc += wz * sB[lzo*360 + j2*180 + k2*90 + gc];
        }
        part[(size_t)bid*PART + item] = acc;
    }
}

// ---------------------------------------------------------------------------
// Gather per-cell partials from the <=8 contributing blocks (deterministic).
// ---------------------------------------------------------------------------
__global__ __launch_bounds__(256)
void k_reduce(const float* __restrict__ part, float* __restrict__ grid)
{
    const int item = blockIdx.x*256 + threadIdx.x;
    if (item >= GOUT) return;
    const int c    = item % 9;
    const int cell = item / 9;
    const int gz = cell / ST0;
    int r = cell % ST0;
    const int gy = r / ST1;  r %= ST1;
    const int gx = r / ST2;
    const int g  = r % ST2;
    float acc = 0.f;
    #pragma unroll
    for (int t = 0; t < 8; ++t) {
        const int i2 = t >> 2, j2 = (t >> 1) & 1, k2 = t & 1;
        const int bz = gz - i2, by = gy - j2, bx = gx - k2;
        if ((unsigned)bz < (unsigned)NBLK && (unsigned)by < (unsigned)NBLK &&
            (unsigned)bx < (unsigned)NBLK)
            acc += part[(size_t)((bz*NBLK + by)*NBLK + bx)*PART + t*90 + g*9 + c];
    }
    grid[cell*CH + c] = acc;
}

// ---------------------------------------------------------------------------
// Fused Gaussian x+y pass over one (label,z) slice held in LDS (18 KB).
// x-blur: 6 half8 LDS reads -> 16 outputs (register sliding window).
// y-blur: 22 half8 reads -> 4 half8 outputs. One 28 MB round-trip saved.
// Grid: 768 blocks = 8 labels x 96 z.
// ---------------------------------------------------------------------------
__global__ __launch_bounds__(256)
void k_gauss_xy(const half8* __restrict__ src, half8* __restrict__ dst)
{
    __shared__ _Float16 sIn[PLANE];
    __shared__ _Float16 sX[PLANE];
    half8* sIn8 = (half8*)sIn;
    half8* sX8  = (half8*)sX;

    const int tid = threadIdx.x;
    const size_t base8 = (size_t)blockIdx.x * PLANE8;

    for (int i = tid; i < PLANE8; i += 256) sIn8[i] = src[base8 + i];
    __syncthreads();

    // x-blur: item = row*6 + seg; outputs x = 16*seg .. 16*seg+15
    for (int it = tid; it < 576; it += 256) {
        const int seg = it % 6;
        const int row = it / 6;
        float w[48];
        #pragma unroll
        for (int k = 0; k < 6; ++k) {
            const int j8 = 2*seg - 2 + k;
            half8 v = h8zero();
            if (j8 >= 0 && j8 < ROW8) v = sIn8[row*ROW8 + j8];
            #pragma unroll
            for (int e = 0; e < 8; ++e) w[k*8 + e] = (float)v[e];
        }
        half8 o0 = h8zero(), o1 = h8zero();
        #pragma unroll
        for (int i = 0; i < 16; ++i) {
            float acc = 0.f;
            #pragma unroll
            for (int t = -9; t <= 9; ++t) acc += GW[t < 0 ? -t : t] * w[i + 16 + t];
            if (i < 8) o0[i] = (_Float16)acc; else o1[i - 8] = (_Float16)acc;
        }
        sX8[row*ROW8 + 2*seg]     = o0;
        sX8[row*ROW8 + 2*seg + 1] = o1;
    }
    __syncthreads();

    // y-blur: item = yseg*12 + x8; outputs y = 4*yseg .. 4*yseg+3
    for (int it = tid; it < 288; it += 256) {
        const int x8   = it % ROW8;
        const int yseg = it / ROW8;
        const int ct = yseg * 4;
        float acc[4][8];
        #pragma unroll
        for (int k = 0; k < 4; ++k)
            #pragma unroll
            for (int e = 0; e < 8; ++e) acc[k][e] = 0.f;
        #pragma unroll
        for (int jj = 0; jj < 22; ++jj) {
            const int j = ct - 9 + jj;
            if (j < 0 || j >= DIM) continue;
            const half8 v = sX8[j*ROW8 + x8];
            float f[8];
            #pragma unroll
            for (int e = 0; e < 8; ++e) f[e] = (float)v[e];
            #pragma unroll
            for (int k = 0; k < 4; ++k) {
                const int d = jj - 9 - k;
                if (d >= -9 && d <= 9) {
                    const float wgt = GW[d < 0 ? -d : d];
                    #pragma unroll
                    for (int e = 0; e < 8; ++e) acc[k][e] += wgt * f[e];
                }
            }
        }
        #pragma unroll
        for (int k = 0; k < 4; ++k) {
            half8 o;
            #pragma unroll
            for (int e = 0; e < 8; ++e) o[e] = (_Float16)acc[k][e];
            dst[base8 + (ct + k)*ROW8 + x8] = o;
        }
    }
}

// ---------------------------------------------------------------------------
// Gaussian z-pass, fp16 io. Thread owns 8 x-halves x 4 outputs along z.
// Grid: 864 blocks (XCD-chunk swizzled).
// ---------------------------------------------------------------------------
__global__ __launch_bounds__(256)
void k_gauss_z(const half8* __restrict__ src, half8* __restrict__ dst)
{
    const int bid = blockIdx.x;
    const int swz = (bid & 7) * (864 >> 3) + (bid >> 3);
    const int u = swz * 256 + threadIdx.x;

    const int x8 = u % ROW8;
    const int yy = (u / ROW8) % DIM;
    const int ztl = u / (ROW8 * DIM);       // zt + 24*l
    const int zt = ztl % (DIM/4);
    const int l  = ztl / (DIM/4);
    const int base8 = l * VOL8 + yy * ROW8 + x8;
    const int ct = zt * 4;

    float acc[4][8];
    #pragma unroll
    for (int k = 0; k < 4; ++k)
        #pragma unroll
        for (int e = 0; e < 8; ++e) acc[k][e] = 0.f;

    #pragma unroll
    for (int jj = 0; jj < 22; ++jj) {
        const int j = ct - 9 + jj;
        if (j < 0 || j >= DIM) continue;
        const half8 v = src[base8 + j*PLANE8];
        float f[8];
        #pragma unroll
        for (int e = 0; e < 8; ++e) f[e] = (float)v[e];
        #pragma unroll
        for (int k = 0; k < 4; ++k) {
            const int d = jj - 9 - k;
            if (d >= -9 && d <= 9) {
                const float wgt = GW[d < 0 ? -d : d];
                #pragma unroll
                for (int e = 0; e < 8; ++e) acc[k][e] += wgt * f[e];
            }
        }
    }
    #pragma unroll
    for (int k = 0; k < 4; ++k) {
        half8 o;
        #pragma unroll
        for (int e = 0; e < 8; ++e) o[e] = (_Float16)acc[k][e];
        dst[base8 + (ct + k)*PLANE8] = o;
    }
}

// ---------------------------------------------------------------------------
// Fused 4-axis [1,2,1]/4 blur: one 81-tap kernel (grid is L2-resident).
// ---------------------------------------------------------------------------
__global__ __launch_bounds__(256)
void k_blur81(const float* __restrict__ src, float* __restrict__ dst)
{
    const int item = blockIdx.x*256 + threadIdx.x;
    if (item >= GOUT) return;
    const int c    = item % 9;
    const int cell = item / 9;
    const int gz = cell / ST0;
    int r = cell % ST0;
    const int gy = r / ST1;  r %= ST1;
    const int gx = r / ST2;
    const int g  = r % ST2;

    const int crd[4] = {gz, gy, gx, g};
    const int ext[4] = {GD0, GD1, GD2, GD3};
    const int str[4] = {ST0, ST1, ST2, 1};
    float wa[4][3];
    int   oa[4][3];
    #pragma unroll
    for (int ax = 0; ax < 4; ++ax)
        #pragma unroll
        for (int dd = 0; dd < 3; ++dd) {
            const int cc = crd[ax] + dd - 1;
            const bool ok = (cc >= 0 && cc < ext[ax]);
            wa[ax][dd] = ok ? (dd == 1 ? 0.5f : 0.25f) : 0.f;
            oa[ax][dd] = ok ? (dd - 1) * str[ax] : 0;
        }

    float acc = 0.f;
    #pragma unroll
    for (int a = 0; a < 3; ++a) {
        const float w0 = wa[0][a];
        #pragma unroll
        for (int b = 0; b < 3; ++b) {
            const float w1 = w0 * wa[1][b];
            #pragma unroll
            for (int d2 = 0; d2 < 3; ++d2) {
                const float w2 = w1 * wa[2][d2];
                const int ob = oa[0][a] + oa[1][b] + oa[2][d2];
                #pragma unroll
                for (int e = 0; e < 3; ++e)
                    acc += w2 * wa[3][e] * src[(cell + ob + oa[3][e])*CH + c];
            }
        }
    }
    dst[cell*CH + c] = acc;
}

// ---------------------------------------------------------------------------
// Final: inline CS=C@S, CB=C@B, slice bilateral grid, normalize,
// Qp = CS@sp + CB@bi, out = softmax(U + Qp). sp is fp16.
// ---------------------------------------------------------------------------
__global__ __launch_bounds__(256)
void k_final(const float* __restrict__ U, const float* __restrict__ img,
             const _Float16* __restrict__ sp, const float* __restrict__ grid,
             const float* __restrict__ Cm, const float* __restrict__ Sw,
             const float* __restrict__ Bw, float* __restrict__ out)
{
    __shared__ float sm[128];
    if (threadIdx.x < 64) {
        const int i = threadIdx.x >> 3, j = threadIdx.x & 7;
        float cs = 0.f, cb = 0.f;
        #pragma unroll
        for (int k = 0; k < 8; ++k) {
            cs += Cm[i*8 + k] * Sw[k*8 + j];
            cb += Cm[i*8 + k] * Bw[k*8 + j];
        }
        sm[threadIdx.x] = cs;
        sm[64 + threadIdx.x] = cb;
    }
    __syncthreads();

    const int vox = blockIdx.x * 256 + threadIdx.x;
    if (vox >= NVOX) return;
    const int z = vox / PLANE;
    const int y = (vox / DIM) % DIM;
    const int x = vox % DIM;
    const int lz = z >> 3, lyc = y >> 3, lxc = x >> 3;
    const float fz = (float)(z & 7) * 0.125f;
    const float fy = (float)(y & 7) * 0.125f;
    const float fx = (float)(x & 7) * 0.125f;
    const float f = img[vox] * 8.0f;
    int li = (int)floorf(f);
    li = li < 0 ? 0 : (li > 8 ? 8 : li);
    const float fi = f - (float)li;
    const float wz[2]  = {1.f - fz, fz};
    const float wyv[2] = {1.f - fy, fy};
    const float wxv[2] = {1.f - fx, fx};
    const float wiv[2] = {1.f - fi, fi};

    float acc[9];
    #pragma unroll
    for (int c = 0; c < 9; ++c) acc[c] = 0.f;

    #pragma unroll
    for (int i2 = 0; i2 < 2; ++i2)
    #pragma unroll
    for (int j2 = 0; j2 < 2; ++j2)
    #pragma unroll
    for (int k2 = 0; k2 < 2; ++k2) {
        const float wsp = wz[i2] * wyv[j2] * wxv[k2];
        const int cellbase = (lz+i2)*ST0 + (lyc+j2)*ST1 + (lxc+k2)*ST2 + li;
        #pragma unroll
        for (int m2 = 0; m2 < 2; ++m2) {
            const float w = wsp * wiv[m2];
            const float* p = &grid[(cellbase + m2) * CH];
            const float4 p0 = *reinterpret_cast<const float4*>(p);
            const float4 p1 = *reinterpret_cast<const float4*>(p + 4);
            acc[0] += w * p0.x; acc[1] += w * p0.y; acc[2] += w * p0.z; acc[3] += w * p0.w;
            acc[4] += w * p1.x; acc[5] += w * p1.y; acc[6] += w * p1.z; acc[7] += w * p1.w;
            acc[8] += w * p[8];
        }
    }
    const float dinv = 1.f / (acc[8] + 1e-8f);
    float bi[8], spv[8], uu[8];
    #pragma unroll
    for (int l = 0; l < 8; ++l) {
        bi[l]  = acc[l] * dinv;
        spv[l] = (float)sp[l*NVOX + vox];
        uu[l]  = U[l*NVOX + vox];
    }
    float v[8];
    float mx = -1e30f;
    #pragma unroll
    for (int i = 0; i < 8; ++i) {
        float t = 0.f;
        #pragma unroll
        for (int l = 0; l < 8; ++l) t += sm[i*8 + l] * spv[l] + sm[64 + i*8 + l] * bi[l];
        v[i] = uu[i] + t;
        mx = fmaxf(mx, v[i]);
    }
    float ssum = 0.f;
    #pragma unroll
    for (int i = 0; i < 8; ++i) { v[i] = expf(v[i] - mx); ssum += v[i]; }
    const float inv = 1.f / ssum;
    #pragma unroll
    for (int i = 0; i < 8; ++i) out[i*NVOX + vox] = v[i] * inv;
}

extern "C" void kernel_launch(void* const* d_in, const int* in_sizes, int n_in,
                              void* d_out, int out_size, void* d_ws, size_t ws_size,
                              hipStream_t stream)
{
    const float* U   = (const float*)d_in[0];
    const float* img = (const float*)d_in[1];
    const float* Sw  = (const float*)d_in[2];
    const float* Bw  = (const float*)d_in[3];
    const float* Cm  = (const float*)d_in[4];
    float* out = (float*)d_out;

    _Float16* qh  = (_Float16*)d_ws;                       // 8*NVOX halves
    _Float16* g1h = qh + (size_t)LBL * NVOX;               // 8*NVOX halves
    float* gridA  = (float*)(g1h + (size_t)LBL * NVOX);    // GSIZE*CH floats
    float* part   = gridA + (size_t)GSIZE * CH;            // NBLKS*PART floats
    float* gridB  = part;                                  // alias (dead after reduce)

    k_softmax_splat<<<NBLKS, 512, 0, stream>>>(U, img, qh, part);
    k_reduce<<<(GOUT + 255)/256, 256, 0, stream>>>(part, gridA);
    k_blur81<<<(GOUT + 255)/256, 256, 0, stream>>>(gridA, gridB);

    k_gauss_xy<<<768, 256, 0, stream>>>((const half8*)qh, (half8*)g1h);  // x+y: qh -> g1h
    k_gauss_z<<<864, 256, 0, stream>>>((const half8*)g1h, (half8*)qh);   // z:   g1h -> qh (= sp)

    k_final<<<(NVOX + 255)/256, 256, 0, stream>>>(U, img, qh, gridB, Cm, Sw, Bw, out);
}